// Round 1
// baseline (1526.022 us; speedup 1.0000x reference)
//
#include <hip/hip_runtime.h>
#include <math.h>

// Problem constants
#define SQ   4      // live sequences (b in 0..3, n == 0 only)
#define LL   64
#define DM   128
#define DI   256
#define DS   16
#define RANK 8

// Per-(seq,layer) scratch chunk in ws (floats):
//   hn   @ 0      (64*128  =  8192)
//   u    @ 8192   (64*256  = 16384)
//   y    @ 24576  (64*256  = 16384)
//   g    @ 40960  (64*256  = 16384)
//   xdbl @ 57344  (64*40   =  2560)
#define CH 65536
// h1 (MLP temp): ws + 16*CH + s*8192.  Total ws use ~4.33 MB.

__device__ __forceinline__ float silu_f(float v) {
    return v / (1.0f + __expf(-v));
}
__device__ __forceinline__ float dot4(float4 a, float4 b) {
    return a.x*b.x + a.y*b.y + a.z*b.z + a.w*b.w;
}
__device__ __forceinline__ float wave_red_sum(float v) {
    v += __shfl_xor(v, 1);  v += __shfl_xor(v, 2);  v += __shfl_xor(v, 4);
    v += __shfl_xor(v, 8);  v += __shfl_xor(v, 16); v += __shfl_xor(v, 32);
    return v;
}

// One workgroup per live sequence. 1024 threads = 16 waves.
//
// B-layout (MLP, out-GEMM, residual, rmsnorm):
//   jp = t&63, rg = t>>6 : cols {jp*2, jp*2+1}, rows rg*4..rg*4+3.
//   Row l lives entirely in wave (l>>2) -> rmsnorm is a pure shfl reduce.
// A-layout (in-GEMM, conv, gating):
//   cg = t&255, rg2 = t>>8 : cols {cg*2, cg*2+1}, rows rg2*16..rg2*16+15.
__global__ __launch_bounds__(1024) void fused_kernel(
    const float* __restrict__ mha_in, const int* __restrict__ mask,
    const float* __restrict__ mlp_w1, const float* __restrict__ mlp_b1,
    const float* __restrict__ mlp_w2, const float* __restrict__ mlp_b2,
    const float* __restrict__ in_proj_w, const float* __restrict__ conv_w,
    const float* __restrict__ conv_b, const float* __restrict__ x_proj_w,
    const float* __restrict__ dt_proj_w, const float* __restrict__ dt_proj_b,
    const float* __restrict__ A_log, const float* __restrict__ D_skip,
    const float* __restrict__ out_proj_w, const float* __restrict__ blk_norm_w,
    const float* __restrict__ norm_f_w,
    float* __restrict__ ws, float* __restrict__ out)
{
    const int s  = blockIdx.x;
    const int t  = threadIdx.x;
    const int jp = t & 63,  rg  = t >> 6;   // B-layout
    const int cg = t & 255, rg2 = t >> 8;   // A-layout

    __shared__ float halo[3][3][256];   // conv halo between row-groups
    __shared__ int   anyv;

    float resid[8];   // resid[r*2+q] = residual[rg*4+r][jp*2+q]

    // ===================== MLP (layer-0 preamble) =====================
    {
        const float* xrow = mha_in + (size_t)s * 524288;   // [l*128 + c], n==0
        float* h1 = ws + 16*CH + s*8192;

        // h1 = gelu(x @ w1^T + b1)
        {
            const float* w0p = mlp_w1 + (size_t)(jp*2)   * 128;
            const float* w1p = mlp_w1 + (size_t)(jp*2+1) * 128;
            const float* xb  = xrow + (rg*4)*128;
            float acc[8] = {0.f,0.f,0.f,0.f,0.f,0.f,0.f,0.f};
            #pragma unroll 2
            for (int k4 = 0; k4 < 32; ++k4) {
                float4 wv0 = *(const float4*)&w0p[k4*4];
                float4 wv1 = *(const float4*)&w1p[k4*4];
                #pragma unroll
                for (int r = 0; r < 4; ++r) {
                    float4 xv = *(const float4*)&xb[r*128 + k4*4];  // broadcast
                    acc[r*2]   += dot4(xv, wv0);
                    acc[r*2+1] += dot4(xv, wv1);
                }
            }
            float b0 = mlp_b1[jp*2], b1 = mlp_b1[jp*2+1];
            #pragma unroll
            for (int r = 0; r < 4; ++r) {
                float v0 = acc[r*2] + b0, v1 = acc[r*2+1] + b1;
                v0 = 0.5f*v0*(1.0f + erff(v0*0.70710678118f));
                v1 = 0.5f*v1*(1.0f + erff(v1*0.70710678118f));
                h1[(rg*4+r)*128 + jp*2]     = v0;
                h1[(rg*4+r)*128 + jp*2 + 1] = v1;
            }
        }
        __syncthreads();
        // residual = h1 @ w2^T + b2   (stays in registers)
        {
            const float* w0p = mlp_w2 + (size_t)(jp*2)   * 128;
            const float* w1p = mlp_w2 + (size_t)(jp*2+1) * 128;
            const float* hb  = h1 + (rg*4)*128;
            float acc[8] = {0.f,0.f,0.f,0.f,0.f,0.f,0.f,0.f};
            #pragma unroll 2
            for (int k4 = 0; k4 < 32; ++k4) {
                float4 wv0 = *(const float4*)&w0p[k4*4];
                float4 wv1 = *(const float4*)&w1p[k4*4];
                #pragma unroll
                for (int r = 0; r < 4; ++r) {
                    float4 xv = *(const float4*)&hb[r*128 + k4*4];  // broadcast
                    acc[r*2]   += dot4(xv, wv0);
                    acc[r*2+1] += dot4(xv, wv1);
                }
            }
            float b0 = mlp_b2[jp*2], b1 = mlp_b2[jp*2+1];
            #pragma unroll
            for (int r = 0; r < 4; ++r) {
                resid[r*2]   = acc[r*2]   + b0;
                resid[r*2+1] = acc[r*2+1] + b1;
            }
        }
    }

    // accA[q*16 + l] : in-GEMM output for col cg*2+q, row rg2*16+l.
    // For cg<128 these are xc (consumed by conv); for cg>=128 they are z
    // (held in registers until the gating phase).
    float accA[32];

    // ===================== layer loop =====================
    for (int layer = 0; layer < 4; ++layer) {
        float* base = ws + (size_t)(s*4 + layer) * CH;
        float* hn_g = base;
        float* u_g  = base + 8192;
        float* y_g  = base + 24576;
        float* g_g  = base + 40960;
        float* xd_g = base + 57344;

        // ---- rmsnorm(residual) -> hn (pure shfl, one wave per 4 rows) ----
        {
            const float bw0 = blk_norm_w[layer*128 + jp*2];
            const float bw1 = blk_norm_w[layer*128 + jp*2 + 1];
            #pragma unroll
            for (int r = 0; r < 4; ++r) {
                float sq = resid[r*2]*resid[r*2] + resid[r*2+1]*resid[r*2+1];
                sq = wave_red_sum(sq);
                float sc = rsqrtf(sq*(1.0f/128.0f) + 1e-5f);
                hn_g[(rg*4+r)*128 + jp*2]     = resid[r*2]  *sc*bw0;
                hn_g[(rg*4+r)*128 + jp*2 + 1] = resid[r*2+1]*sc*bw1;
            }
        }
        __syncthreads();

        // ---- in-GEMM: xz = hn @ in_w^T  (A-layout, broadcast hn rows) ----
        {
            const float* wr0 = in_proj_w + ((size_t)layer*512 + cg*2)*128;
            const float* wr1 = wr0 + 128;
            #pragma unroll
            for (int i = 0; i < 32; ++i) accA[i] = 0.f;
            #pragma unroll 1
            for (int st = 0; st < 2; ++st) {             // two 8-row subtiles
                const float* hb = hn_g + (rg2*16 + st*8)*128;
                #pragma unroll 2
                for (int k4 = 0; k4 < 32; ++k4) {
                    float4 wv0 = *(const float4*)&wr0[k4*4];
                    float4 wv1 = *(const float4*)&wr1[k4*4];
                    #pragma unroll
                    for (int l = 0; l < 8; ++l) {
                        float4 hv = *(const float4*)&hb[l*128 + k4*4];  // broadcast
                        accA[st*8 + l]      += dot4(hv, wv0);
                        accA[16 + st*8 + l] += dot4(hv, wv1);
                    }
                }
            }
        }
        // halo: rows 13..15 of each row-group for the next row-group's conv
        if (rg2 < 3 && cg < 128) {
            #pragma unroll
            for (int i = 0; i < 3; ++i) {
                halo[rg2][i][cg*2]     = accA[13 + i];
                halo[rg2][i][cg*2 + 1] = accA[16 + 13 + i];
            }
        }
        __syncthreads();

        // ---- causal conv1d + silu -> u (register-resident xc) ----
        if (cg < 128) {
            #pragma unroll
            for (int q = 0; q < 2; ++q) {
                const int d = cg*2 + q;
                const float* cw = conv_w + ((size_t)layer*256 + d)*4;
                float cw0 = cw[0], cw1 = cw[1], cw2 = cw[2], cw3 = cw[3];
                float cb = conv_b[layer*256 + d];
                float xm3, xm2, xm1;
                if (rg2 == 0) { xm3 = 0.f; xm2 = 0.f; xm1 = 0.f; }
                else {
                    xm3 = halo[rg2-1][0][d];
                    xm2 = halo[rg2-1][1][d];
                    xm1 = halo[rg2-1][2][d];
                }
                float* up = u_g + (rg2*16)*256 + d;
                #pragma unroll
                for (int l = 0; l < 16; ++l) {
                    float x0 = accA[q*16 + l];
                    float v  = cb + cw0*xm3 + cw1*xm2 + cw2*xm1 + cw3*x0;
                    up[l*256] = silu_f(v);
                    xm3 = xm2; xm2 = xm1; xm1 = x0;
                }
            }
        }
        __syncthreads();

        // ---- xproj: xdbl = u @ x_proj_w^T  (64 x 40, K=256) ----
        if (t < 640) {
            const int jx = t % 40, rq = t / 40;        // 40 cols x 16 row-groups
            const float* xw = x_proj_w + ((size_t)layer*40 + jx)*256;
            const float* ub = u_g + (rq*4)*256;
            float acc[4] = {0.f,0.f,0.f,0.f};
            #pragma unroll 2
            for (int k4 = 0; k4 < 64; ++k4) {
                float4 wv = *(const float4*)&xw[k4*4];
                #pragma unroll
                for (int r = 0; r < 4; ++r) {
                    float4 uv = *(const float4*)&ub[r*256 + k4*4];  // broadcast
                    acc[r] += dot4(uv, wv);
                }
            }
            #pragma unroll
            for (int r = 0; r < 4; ++r) xd_g[(rq*4+r)*40 + jx] = acc[r];
        }
        __syncthreads();

        // ---- selective scan: 256 channels x 4 sub-lanes (4 states each) ----
        {
            const int d = t >> 2, sub = t & 3;
            const float* Ab = A_log + ((size_t)layer*256 + d)*16 + sub*4;
            float A0 = -__expf(Ab[0]), A1 = -__expf(Ab[1]);
            float A2 = -__expf(Ab[2]), A3 = -__expf(Ab[3]);
            float Dsk = D_skip[layer*256 + d];
            float dtb = dt_proj_b[layer*256 + d];
            const float* dwp = dt_proj_w + ((size_t)layer*256 + d)*8;
            float4 dwa = *(const float4*)&dwp[0];
            float4 dwb = *(const float4*)&dwp[4];
            float h0 = 0.f, h1v = 0.f, h2v = 0.f, h3v = 0.f;
            for (int l = 0; l < 64; ++l) {
                const float* xr = xd_g + l*40;
                float4 xa  = *(const float4*)xr;          // broadcast
                float4 xb2 = *(const float4*)(xr + 4);    // broadcast
                float pre = dtb + xa.x*dwa.x + xa.y*dwa.y + xa.z*dwa.z + xa.w*dwa.w
                                + xb2.x*dwb.x + xb2.y*dwb.y + xb2.z*dwb.z + xb2.w*dwb.w;
                float sp = (pre > 20.f) ? pre : log1pf(__expf(pre));
                float uv = u_g[l*256 + d];
                float du = sp * uv;
                float4 B4 = *(const float4*)(xr + 8  + sub*4);
                float4 C4 = *(const float4*)(xr + 24 + sub*4);
                float dA, yp;
                dA = __expf(sp*A0); h0  = dA*h0  + du*B4.x; yp  = h0 *C4.x;
                dA = __expf(sp*A1); h1v = dA*h1v + du*B4.y; yp += h1v*C4.y;
                dA = __expf(sp*A2); h2v = dA*h2v + du*B4.z; yp += h2v*C4.z;
                dA = __expf(sp*A3); h3v = dA*h3v + du*B4.w; yp += h3v*C4.w;
                yp += __shfl_xor(yp, 1);
                yp += __shfl_xor(yp, 2);
                if (sub == 0) y_g[l*256 + d] = yp + uv*Dsk;
            }
        }
        __syncthreads();

        // ---- gating: g = y * silu(z)  (z still in accA registers) ----
        if (cg >= 128) {
            #pragma unroll
            for (int q = 0; q < 2; ++q) {
                const int d = (cg - 128)*2 + q;
                const float* yp = y_g + (rg2*16)*256 + d;
                float*       gp = g_g + (rg2*16)*256 + d;
                #pragma unroll
                for (int l = 0; l < 16; ++l)
                    gp[l*256] = yp[l*256] * silu_f(accA[q*16 + l]);
            }
        }
        __syncthreads();

        // ---- out-GEMM + residual update (B-layout) ----
        {
            const float* o0 = out_proj_w + ((size_t)layer*128 + jp*2)*256;
            const float* o1 = o0 + 256;
            const float* gb = g_g + (rg*4)*256;
            float acc[8] = {0.f,0.f,0.f,0.f,0.f,0.f,0.f,0.f};
            #pragma unroll 2
            for (int k4 = 0; k4 < 64; ++k4) {
                float4 wv0 = *(const float4*)&o0[k4*4];
                float4 wv1 = *(const float4*)&o1[k4*4];
                #pragma unroll
                for (int r = 0; r < 4; ++r) {
                    float4 gv = *(const float4*)&gb[r*256 + k4*4];  // broadcast
                    acc[r*2]   += dot4(gv, wv0);
                    acc[r*2+1] += dot4(gv, wv1);
                }
            }
            #pragma unroll
            for (int r = 0; r < 8; ++r) resid[r] += acc[r];
        }
        // no barrier needed: next phase writes a different (layer-rotated) chunk
    }

    // ===================== final: row 63 norm + key_valid mask =====================
    if (t == 0) anyv = 0;
    __syncthreads();
    if (t < 64) { if (mask[s*4096 + t] != 0) anyv = 1; }   // benign race
    __syncthreads();
    if (rg == 15) {   // wave 15 holds row 63 (resid[6], resid[7])
        float sq = resid[6]*resid[6] + resid[7]*resid[7];
        sq = wave_red_sum(sq);
        float sc = rsqrtf(sq*(1.0f/128.0f) + 1e-5f);
        float v0 = resid[6]*sc*norm_f_w[jp*2];
        float v1 = resid[7]*sc*norm_f_w[jp*2 + 1];
        out[s*128 + jp*2]     = anyv ? v0 : 0.f;
        out[s*128 + jp*2 + 1] = anyv ? v1 : 0.f;
    }
}

// ---------------------------------------------------------------------------
extern "C" void kernel_launch(void* const* d_in, const int* in_sizes, int n_in,
                              void* d_out, int out_size, void* d_ws, size_t ws_size,
                              hipStream_t stream) {
    (void)in_sizes; (void)n_in; (void)out_size; (void)ws_size;
    const float* mha_in     = (const float*)d_in[0];
    const int*   mask       = (const int*)  d_in[1];
    const float* mlp_w1     = (const float*)d_in[2];
    const float* mlp_b1     = (const float*)d_in[3];
    const float* mlp_w2     = (const float*)d_in[4];
    const float* mlp_b2     = (const float*)d_in[5];
    const float* in_proj_w  = (const float*)d_in[6];
    const float* conv_w     = (const float*)d_in[7];
    const float* conv_b     = (const float*)d_in[8];
    const float* x_proj_w   = (const float*)d_in[9];
    const float* dt_proj_w  = (const float*)d_in[10];
    const float* dt_proj_b  = (const float*)d_in[11];
    const float* A_log      = (const float*)d_in[12];
    const float* D_skip     = (const float*)d_in[13];
    const float* out_proj_w = (const float*)d_in[14];
    const float* blk_norm_w = (const float*)d_in[15];
    const float* norm_f_w   = (const float*)d_in[16];

    fused_kernel<<<SQ, 1024, 0, stream>>>(
        mha_in, mask, mlp_w1, mlp_b1, mlp_w2, mlp_b2,
        in_proj_w, conv_w, conv_b, x_proj_w, dt_proj_w, dt_proj_b,
        A_log, D_skip, out_proj_w, blk_norm_w, norm_f_w,
        (float*)d_ws, (float*)d_out);
}

// Round 2
// 427.924 us; speedup vs baseline: 3.5661x; 3.5661x over previous
//
#include <hip/hip_runtime.h>
#include <hip/hip_cooperative_groups.h>
#include <math.h>

namespace cg = cooperative_groups;

#define NWG  64
#define NTHR 512

// ws float offsets (all buffers written before read every layer)
#define WS_XZ 0        // 256 rows x 512
#define WS_U  131072   // 256 x 256
#define WS_DT 196608   // 256 x 256
#define WS_Y  262144   // 256 x 256
#define WS_XD 327680   // 256 x 40

__device__ __forceinline__ float silu_f(float v) { return v / (1.0f + __expf(-v)); }
__device__ __forceinline__ float dot4(float4 a, float4 b) {
    return a.x*b.x + a.y*b.y + a.z*b.z + a.w*b.w;
}
__device__ __forceinline__ float wave_red_sum(float v) {
    v += __shfl_xor(v, 1);  v += __shfl_xor(v, 2);  v += __shfl_xor(v, 4);
    v += __shfl_xor(v, 8);  v += __shfl_xor(v, 16); v += __shfl_xor(v, 32);
    return v;
}

// 64 wgs x 512 threads, cooperative. wg owns rows r0..r0+3 (r = s*64 + l).
// Register residual: thread t owns (row r0 + (t>>7), col t&127).
__global__ __launch_bounds__(NTHR) void fused_kernel(
    const float* __restrict__ mha_in, const int* __restrict__ mask,
    const float* __restrict__ mlp_w1, const float* __restrict__ mlp_b1,
    const float* __restrict__ mlp_w2, const float* __restrict__ mlp_b2,
    const float* __restrict__ in_proj_w, const float* __restrict__ conv_w,
    const float* __restrict__ conv_b, const float* __restrict__ x_proj_w,
    const float* __restrict__ dt_proj_w, const float* __restrict__ dt_proj_b,
    const float* __restrict__ A_log, const float* __restrict__ D_skip,
    const float* __restrict__ out_proj_w, const float* __restrict__ blk_norm_w,
    const float* __restrict__ norm_f_w,
    float* __restrict__ ws, float* __restrict__ out)
{
    cg::grid_group grid = cg::this_grid();
    const int wg = blockIdx.x;
    const int t  = threadIdx.x;
    const int s  = wg >> 4;          // sequence 0..3
    const int r0 = wg << 2;          // first owned row
    const int h  = t >> 7;           // 0..3  (owned row index)
    const int c  = t & 127;          // owned column
    const int wave = t >> 6;

    float* xz   = ws + WS_XZ;
    float* u_g  = ws + WS_U;
    float* dt_g = ws + WS_DT;
    float* y_g  = ws + WS_Y;
    float* xd_g = ws + WS_XD;

    __shared__ float bufA[4][256];   // h1 / u / g
    __shared__ float bufB[4][128];   // x / hn
    __shared__ float xdS[4][40];
    __shared__ float part[8];
    __shared__ int   anyv;

    float resid;

    // ===================== MLP preamble (row-local) =====================
    bufB[h][c] = mha_in[(size_t)s*524288 + (size_t)((r0 & 63) + h)*128 + c];
    __syncthreads();
    {
        const float* w = mlp_w1 + (size_t)c * 128;
        float acc = 0.f;
        #pragma unroll 4
        for (int k4 = 0; k4 < 32; ++k4)
            acc += dot4(*(const float4*)&bufB[h][k4*4], *(const float4*)&w[k4*4]);
        float v = acc + mlp_b1[c];
        v = 0.5f*v*(1.0f + erff(v*0.70710678118f));
        bufA[h][c] = v;                       // h1 (cols 0..127 of bufA)
    }
    __syncthreads();
    {
        const float* w = mlp_w2 + (size_t)c * 128;
        float acc = 0.f;
        #pragma unroll 4
        for (int k4 = 0; k4 < 32; ++k4)
            acc += dot4(*(const float4*)&bufA[h][k4*4], *(const float4*)&w[k4*4]);
        resid = acc + mlp_b2[c];
    }
    __syncthreads();

    // ===================== layer loop =====================
    for (int layer = 0; layer < 4; ++layer) {
        // ---- rmsnorm(resid) -> bufB (hn) ----
        {
            float sq = wave_red_sum(resid*resid);
            if ((t & 63) == 0) part[wave] = sq;
        }
        __syncthreads();
        {
            float sr = part[h*2] + part[h*2 + 1];
            float sc = rsqrtf(sr*(1.0f/128.0f) + 1e-5f);
            bufB[h][c] = resid * sc * blk_norm_w[layer*128 + c];
        }
        __syncthreads();

        // ---- in-GEMM: xz[r0..r0+3][j=t] , K=128 from LDS broadcast ----
        {
            const float* w = in_proj_w + ((size_t)layer*512 + t)*128;
            float a0=0.f, a1=0.f, a2=0.f, a3=0.f;
            #pragma unroll 4
            for (int k4 = 0; k4 < 32; ++k4) {
                float4 wv = *(const float4*)&w[k4*4];
                a0 += dot4(*(const float4*)&bufB[0][k4*4], wv);
                a1 += dot4(*(const float4*)&bufB[1][k4*4], wv);
                a2 += dot4(*(const float4*)&bufB[2][k4*4], wv);
                a3 += dot4(*(const float4*)&bufB[3][k4*4], wv);
            }
            xz[(size_t)(r0+0)*512 + t] = a0;
            xz[(size_t)(r0+1)*512 + t] = a1;
            xz[(size_t)(r0+2)*512 + t] = a2;
            xz[(size_t)(r0+3)*512 + t] = a3;
        }
        grid.sync();   // S1: xz visible everywhere

        // ---- conv + silu -> u (own rows, halo via global xz) ----
        {
            int d = t & 255, half = t >> 8;         // 2 rows per thread
            int la = (r0 & 63) + half*2;
            int rb = s*64;
            float x0 = (la-3 >= 0) ? xz[(size_t)(rb+la-3)*512 + d] : 0.f;
            float x1 = (la-2 >= 0) ? xz[(size_t)(rb+la-2)*512 + d] : 0.f;
            float x2 = (la-1 >= 0) ? xz[(size_t)(rb+la-1)*512 + d] : 0.f;
            float x3 = xz[(size_t)(rb+la  )*512 + d];
            float x4 = xz[(size_t)(rb+la+1)*512 + d];
            float4 cw = *(const float4*)&conv_w[((size_t)layer*256 + d)*4];
            float cb = conv_b[layer*256 + d];
            float ua = silu_f(cb + cw.x*x0 + cw.y*x1 + cw.z*x2 + cw.w*x3);
            float ub = silu_f(cb + cw.x*x1 + cw.y*x2 + cw.z*x3 + cw.w*x4);
            bufA[half*2  ][d] = ua;
            bufA[half*2+1][d] = ub;
            u_g[(size_t)(r0 + half*2    )*256 + d] = ua;
            u_g[(size_t)(r0 + half*2 + 1)*256 + d] = ub;
        }
        __syncthreads();

        // ---- xproj: xdbl[4 rows][40], K=256 from LDS ----
        if (t < 160) {
            int rq = t & 3, jx = t >> 2;
            const float* xw = x_proj_w + ((size_t)layer*40 + jx)*256;
            float acc = 0.f;
            #pragma unroll 4
            for (int k4 = 0; k4 < 64; ++k4)
                acc += dot4(*(const float4*)&bufA[rq][k4*4], *(const float4*)&xw[k4*4]);
            xdS[rq][jx] = acc;
            xd_g[(size_t)(r0+rq)*40 + jx] = acc;
        }
        __syncthreads();

        // ---- dt = softplus(xdbl[:, :8] @ dt_w^T + dt_b) ----
        {
            int d = t & 255, half = t >> 8;
            const float* dw = dt_proj_w + ((size_t)layer*256 + d)*8;
            float4 wa = *(const float4*)&dw[0];
            float4 wb = *(const float4*)&dw[4];
            float b = dt_proj_b[layer*256 + d];
            #pragma unroll
            for (int q = 0; q < 2; ++q) {
                int rloc = half*2 + q;
                float4 xa = *(const float4*)&xdS[rloc][0];
                float4 xb = *(const float4*)&xdS[rloc][4];
                float pre = b + dot4(xa, wa) + dot4(xb, wb);
                float sp = (pre > 20.f) ? pre : log1pf(__expf(pre));
                dt_g[(size_t)(r0+rloc)*256 + d] = sp;
            }
        }
        grid.sync();   // S2: u, dt, xd visible everywhere

        // ---- selective scan: wg handles 16 channels of its seq ----
        if (t < 64) {
            int dloc = t >> 2, sub = t & 3;
            int d = (wg & 15)*16 + dloc;
            int base = s*64;
            const float* Ab = A_log + ((size_t)layer*256 + d)*16 + sub*4;
            float A0 = -__expf(Ab[0]), A1 = -__expf(Ab[1]);
            float A2 = -__expf(Ab[2]), A3 = -__expf(Ab[3]);
            float Dsk = D_skip[layer*256 + d];
            float h0 = 0.f, h1v = 0.f, h2v = 0.f, h3v = 0.f;
            float dtv = dt_g[(size_t)base*256 + d];
            float uv  = u_g [(size_t)base*256 + d];
            float4 B4 = *(const float4*)&xd_g[(size_t)base*40 + 8  + sub*4];
            float4 C4 = *(const float4*)&xd_g[(size_t)base*40 + 24 + sub*4];
            for (int l = 0; l < 64; ++l) {
                float dtn = 0.f, un = 0.f; float4 Bn = {0,0,0,0}, Cn = {0,0,0,0};
                if (l < 63) {
                    int rn = base + l + 1;
                    dtn = dt_g[(size_t)rn*256 + d];
                    un  = u_g [(size_t)rn*256 + d];
                    Bn  = *(const float4*)&xd_g[(size_t)rn*40 + 8  + sub*4];
                    Cn  = *(const float4*)&xd_g[(size_t)rn*40 + 24 + sub*4];
                }
                float du = dtv * uv;
                float dA, yp;
                dA = __expf(dtv*A0); h0  = dA*h0  + du*B4.x; yp  = h0 *C4.x;
                dA = __expf(dtv*A1); h1v = dA*h1v + du*B4.y; yp += h1v*C4.y;
                dA = __expf(dtv*A2); h2v = dA*h2v + du*B4.z; yp += h2v*C4.z;
                dA = __expf(dtv*A3); h3v = dA*h3v + du*B4.w; yp += h3v*C4.w;
                yp += __shfl_xor(yp, 1);
                yp += __shfl_xor(yp, 2);
                if (sub == 0) y_g[(size_t)(base+l)*256 + d] = yp + uv*Dsk;
                dtv = dtn; uv = un; B4 = Bn; C4 = Cn;
            }
        }
        grid.sync();   // S3: y visible everywhere

        // ---- gate: g = y * silu(z) -> bufA (own rows) ----
        {
            int d = t & 255, half = t >> 8;
            #pragma unroll
            for (int q = 0; q < 2; ++q) {
                int rloc = half*2 + q; int r = r0 + rloc;
                float z = xz[(size_t)r*512 + 256 + d];
                bufA[rloc][d] = y_g[(size_t)r*256 + d] * silu_f(z);
            }
        }
        __syncthreads();

        // ---- out-GEMM + residual update (thread-local resid) ----
        {
            const float* w = out_proj_w + ((size_t)layer*128 + c)*256;
            float acc = 0.f;
            #pragma unroll 4
            for (int k4 = 0; k4 < 64; ++k4)
                acc += dot4(*(const float4*)&bufA[h][k4*4], *(const float4*)&w[k4*4]);
            resid += acc;
        }
        __syncthreads();
    }

    // ===================== final: row 63 of each seq =====================
    if (t == 0) anyv = 0;
    __syncthreads();
    if ((wg & 15) == 15) {
        if (t < 64 && mask[s*4096 + t] != 0) anyv = 1;   // benign race
    }
    __syncthreads();
    if ((wg & 15) == 15) {
        float sq = wave_red_sum(resid*resid);
        if ((t & 63) == 0) part[wave] = sq;
    }
    __syncthreads();
    if ((wg & 15) == 15 && h == 3) {
        float sr = part[6] + part[7];
        float sc = rsqrtf(sr*(1.0f/128.0f) + 1e-5f);
        float o  = resid * sc * norm_f_w[c];
        out[s*128 + c] = anyv ? o : 0.f;
    }
}

// ---------------------------------------------------------------------------
extern "C" void kernel_launch(void* const* d_in, const int* in_sizes, int n_in,
                              void* d_out, int out_size, void* d_ws, size_t ws_size,
                              hipStream_t stream) {
    (void)in_sizes; (void)n_in; (void)out_size; (void)ws_size;
    const float* mha_in     = (const float*)d_in[0];
    const int*   mask       = (const int*)  d_in[1];
    const float* mlp_w1     = (const float*)d_in[2];
    const float* mlp_b1     = (const float*)d_in[3];
    const float* mlp_w2     = (const float*)d_in[4];
    const float* mlp_b2     = (const float*)d_in[5];
    const float* in_proj_w  = (const float*)d_in[6];
    const float* conv_w     = (const float*)d_in[7];
    const float* conv_b     = (const float*)d_in[8];
    const float* x_proj_w   = (const float*)d_in[9];
    const float* dt_proj_w  = (const float*)d_in[10];
    const float* dt_proj_b  = (const float*)d_in[11];
    const float* A_log      = (const float*)d_in[12];
    const float* D_skip     = (const float*)d_in[13];
    const float* out_proj_w = (const float*)d_in[14];
    const float* blk_norm_w = (const float*)d_in[15];
    const float* norm_f_w   = (const float*)d_in[16];
    float* ws  = (float*)d_ws;
    float* out = (float*)d_out;

    void* args[] = {
        (void*)&mha_in, (void*)&mask, (void*)&mlp_w1, (void*)&mlp_b1,
        (void*)&mlp_w2, (void*)&mlp_b2, (void*)&in_proj_w, (void*)&conv_w,
        (void*)&conv_b, (void*)&x_proj_w, (void*)&dt_proj_w, (void*)&dt_proj_b,
        (void*)&A_log, (void*)&D_skip, (void*)&out_proj_w, (void*)&blk_norm_w,
        (void*)&norm_f_w, (void*)&ws, (void*)&out
    };
    hipLaunchCooperativeKernel((void*)fused_kernel, dim3(NWG), dim3(NTHR),
                               args, 0, stream);
}

// Round 3
// 290.876 us; speedup vs baseline: 5.2463x; 1.4712x over previous
//
#include <hip/hip_runtime.h>
#include <math.h>

#define NWG  64
#define NTHR 512

// ws layout (floats). ws[0..63] = barrier epoch counters (uint), host-zeroed.
#define WS_XZ 64                    // 256 x 512
#define WS_DT (WS_XZ + 131072)      // 256 x 256
#define WS_DU (WS_DT + 65536)       // 256 x 256  (du = dt*u)
#define WS_BC (WS_DU + 65536)       // 256 x 32
#define WS_Y  (WS_BC + 8192)        // 256 x 256

__device__ __forceinline__ float silu_f(float v) { return v / (1.0f + __expf(-v)); }
__device__ __forceinline__ float dot4(float4 a, float4 b) {
    return a.x*b.x + a.y*b.y + a.z*b.z + a.w*b.w;
}
__device__ __forceinline__ float wave_red_sum(float v) {
    v += __shfl_xor(v, 1);  v += __shfl_xor(v, 2);  v += __shfl_xor(v, 4);
    v += __shfl_xor(v, 8);  v += __shfl_xor(v, 16); v += __shfl_xor(v, 32);
    return v;
}

// Per-sequence barrier over 16 wgs. Each (layer,point,seq) gets its own slot,
// so no sense reversal is needed. Agent-scope release/acquire handles
// cross-XCD visibility.
__device__ __forceinline__ void seq_barrier(unsigned* slot) {
    __syncthreads();
    if (threadIdx.x == 0) {
        __hip_atomic_fetch_add(slot, 1u, __ATOMIC_RELEASE, __HIP_MEMORY_SCOPE_AGENT);
        while (__hip_atomic_load(slot, __ATOMIC_ACQUIRE, __HIP_MEMORY_SCOPE_AGENT) < 16u) {
            __builtin_amdgcn_s_sleep(1);
        }
    }
    __syncthreads();
}

// 64 wgs x 512 threads, cooperative launch (co-residency guarantee).
// seq = wg & 3  (spreads each seq's wgs over few XCDs with %8 round-robin),
// row-block rb = wg >> 2 : owns rows l0..l0+3 (l0 = rb*4) of its seq.
// Register residual: thread t owns (row h = t>>7, col c = t&127).
__global__ __launch_bounds__(NTHR) void fused_kernel(
    const float* __restrict__ mha_in, const int* __restrict__ mask,
    const float* __restrict__ mlp_w1, const float* __restrict__ mlp_b1,
    const float* __restrict__ mlp_w2, const float* __restrict__ mlp_b2,
    const float* __restrict__ in_proj_w, const float* __restrict__ conv_w,
    const float* __restrict__ conv_b, const float* __restrict__ x_proj_w,
    const float* __restrict__ dt_proj_w, const float* __restrict__ dt_proj_b,
    const float* __restrict__ A_log, const float* __restrict__ D_skip,
    const float* __restrict__ out_proj_w, const float* __restrict__ blk_norm_w,
    const float* __restrict__ norm_f_w,
    float* __restrict__ ws, float* __restrict__ out)
{
    const int wg = blockIdx.x;
    const int t  = threadIdx.x;
    const int s  = wg & 3;           // sequence
    const int rb = wg >> 2;          // row-block within seq (0..15)
    const int l0 = rb * 4;           // first owned local row
    const int r0 = s*64 + l0;        // first owned global row
    const int d0 = rb * 16;          // scan channel base
    const int h  = t >> 7;           // owned row 0..3
    const int c  = t & 127;          // owned col
    const int wave = t >> 6;

    unsigned* bar = (unsigned*)ws;
    float* xz  = ws + WS_XZ;
    float* dtg = ws + WS_DT;
    float* dug = ws + WS_DU;
    float* bcg = ws + WS_BC;
    float* yg  = ws + WS_Y;

    __shared__ float bufA[4][256];   // h1 / u (kept live through gate)
    __shared__ float bufG[4][256];   // g = (y + u*Dsk)*silu(z)
    __shared__ float bufB[4][128];   // x / hn
    __shared__ float xdS[4][40];
    __shared__ float sdt[64][16];    // staged dt   [l][ch]
    __shared__ float sdu[64][16];    // staged dt*u [l][ch]
    __shared__ float sbc[64][32];    // staged B,C  [l][0..15=B,16..31=C]
    __shared__ float pOut[4][4][128];
    __shared__ float part[8];
    __shared__ int   anyv;

    float resid;

    // ===================== MLP preamble (row-local) =====================
    bufB[h][c] = mha_in[(size_t)s*524288 + (size_t)(l0 + h)*128 + c];
    __syncthreads();
    {
        const float* w = mlp_w1 + (size_t)c * 128;
        float acc = 0.f;
        #pragma unroll 8
        for (int k4 = 0; k4 < 32; ++k4)
            acc += dot4(*(const float4*)&bufB[h][k4*4], *(const float4*)&w[k4*4]);
        float v = acc + mlp_b1[c];
        v = 0.5f*v*(1.0f + erff(v*0.70710678118f));
        bufA[h][c] = v;
    }
    __syncthreads();
    {
        const float* w = mlp_w2 + (size_t)c * 128;
        float acc = 0.f;
        #pragma unroll 8
        for (int k4 = 0; k4 < 32; ++k4)
            acc += dot4(*(const float4*)&bufA[h][k4*4], *(const float4*)&w[k4*4]);
        resid = acc + mlp_b2[c];
    }
    __syncthreads();

    // ===================== layer loop =====================
    for (int layer = 0; layer < 4; ++layer) {
        unsigned* slotbase = bar + (layer*3)*4 + s;

        // ---- rmsnorm(resid) -> bufB (hn) ----
        {
            float sq = wave_red_sum(resid*resid);
            if ((t & 63) == 0) part[wave] = sq;
        }
        __syncthreads();
        {
            float sr = part[h*2] + part[h*2 + 1];
            float sc = rsqrtf(sr*(1.0f/128.0f) + 1e-5f);
            bufB[h][c] = resid * sc * blk_norm_w[layer*128 + c];
        }
        __syncthreads();

        // ---- in-GEMM: xz[r0..r0+3][j=t], K=128, hn broadcast from LDS ----
        {
            const float* w = in_proj_w + ((size_t)layer*512 + t)*128;
            float a0=0.f, a1=0.f, a2=0.f, a3=0.f;
            #pragma unroll 8
            for (int k4 = 0; k4 < 32; ++k4) {
                float4 wv = *(const float4*)&w[k4*4];
                a0 += dot4(*(const float4*)&bufB[0][k4*4], wv);
                a1 += dot4(*(const float4*)&bufB[1][k4*4], wv);
                a2 += dot4(*(const float4*)&bufB[2][k4*4], wv);
                a3 += dot4(*(const float4*)&bufB[3][k4*4], wv);
            }
            xz[(size_t)(r0+0)*512 + t] = a0;
            xz[(size_t)(r0+1)*512 + t] = a1;
            xz[(size_t)(r0+2)*512 + t] = a2;
            xz[(size_t)(r0+3)*512 + t] = a3;
        }
        seq_barrier(slotbase + 0*4);   // S1: xz visible within seq

        // ---- conv + silu -> u in bufA (halo via global xz) ----
        {
            int d = t & 255, half = t >> 8;           // 2 rows per thread
            int la = l0 + half*2;
            int rbase = s*64;
            float x0 = (la-3 >= 0) ? xz[(size_t)(rbase+la-3)*512 + d] : 0.f;
            float x1 = (la-2 >= 0) ? xz[(size_t)(rbase+la-2)*512 + d] : 0.f;
            float x2 = (la-1 >= 0) ? xz[(size_t)(rbase+la-1)*512 + d] : 0.f;
            float x3 = xz[(size_t)(rbase+la  )*512 + d];
            float x4 = xz[(size_t)(rbase+la+1)*512 + d];
            float4 cw = *(const float4*)&conv_w[((size_t)layer*256 + d)*4];
            float cb = conv_b[layer*256 + d];
            bufA[half*2  ][d] = silu_f(cb + cw.x*x0 + cw.y*x1 + cw.z*x2 + cw.w*x3);
            bufA[half*2+1][d] = silu_f(cb + cw.x*x1 + cw.y*x2 + cw.z*x3 + cw.w*x4);
        }
        __syncthreads();

        // ---- xproj: xdbl[4][40], K=256 from LDS ----
        if (t < 160) {
            int rq = t & 3, jx = t >> 2;
            const float* xw = x_proj_w + ((size_t)layer*40 + jx)*256;
            float acc = 0.f;
            #pragma unroll 8
            for (int k4 = 0; k4 < 64; ++k4)
                acc += dot4(*(const float4*)&bufA[rq][k4*4], *(const float4*)&xw[k4*4]);
            xdS[rq][jx] = acc;
        }
        __syncthreads();

        // ---- dt = softplus(...) ; write dt and du = dt*u ----
        {
            int d = t & 255, half = t >> 8;
            const float* dw = dt_proj_w + ((size_t)layer*256 + d)*8;
            float4 wa = *(const float4*)&dw[0];
            float4 wb = *(const float4*)&dw[4];
            float b = dt_proj_b[layer*256 + d];
            #pragma unroll
            for (int q = 0; q < 2; ++q) {
                int rloc = half*2 + q;
                float4 xa = *(const float4*)&xdS[rloc][0];
                float4 xb = *(const float4*)&xdS[rloc][4];
                float pre = b + dot4(xa, wa) + dot4(xb, wb);
                float sp = (pre > 20.f) ? pre : log1pf(__expf(pre));
                dtg[(size_t)(r0+rloc)*256 + d] = sp;
                dug[(size_t)(r0+rloc)*256 + d] = sp * bufA[rloc][d];
            }
        }
        // ---- pack B,C ----
        if (t < 128) {
            int r = t >> 5, j = t & 31;
            bcg[(size_t)(r0+r)*32 + j] = xdS[r][8 + j];
        }
        seq_barrier(slotbase + 1*4);   // S2: dt, du, B, C visible within seq

        // ---- stage scan inputs for channels d0..d0+15 into LDS ----
        if (t < 256) {
            int l = t >> 2, q = t & 3;
            *(float4*)&sdt[l][q*4] = *(const float4*)&dtg[(size_t)(s*64+l)*256 + d0 + q*4];
        } else {
            int tt = t - 256; int l = tt >> 2, q = tt & 3;
            *(float4*)&sdu[l][q*4] = *(const float4*)&dug[(size_t)(s*64+l)*256 + d0 + q*4];
        }
        {
            int l = t >> 3, q = t & 7;
            *(float4*)&sbc[l][q*4] = *(const float4*)&bcg[(size_t)(s*64+l)*32 + q*4];
        }
        __syncthreads();

        // ---- selective scan from LDS: 16 channels x 4 sub-lanes ----
        if (t < 64) {
            const int dloc = t >> 2, sub = t & 3, d = d0 + dloc;
            const float* Ab = A_log + ((size_t)layer*256 + d)*16 + sub*4;
            float A0 = -__expf(Ab[0]), A1 = -__expf(Ab[1]);
            float A2 = -__expf(Ab[2]), A3 = -__expf(Ab[3]);
            float h0 = 0.f, h1v = 0.f, h2v = 0.f, h3v = 0.f;
            #pragma unroll 4
            for (int l = 0; l < 64; ++l) {
                float dtv = sdt[l][dloc];
                float duv = sdu[l][dloc];
                float4 B4 = *(const float4*)&sbc[l][sub*4];
                float4 C4 = *(const float4*)&sbc[l][16 + sub*4];
                float dA, yp;
                dA = __expf(dtv*A0); h0  = dA*h0  + duv*B4.x; yp  = h0 *C4.x;
                dA = __expf(dtv*A1); h1v = dA*h1v + duv*B4.y; yp += h1v*C4.y;
                dA = __expf(dtv*A2); h2v = dA*h2v + duv*B4.z; yp += h2v*C4.z;
                dA = __expf(dtv*A3); h3v = dA*h3v + duv*B4.w; yp += h3v*C4.w;
                yp += __shfl_xor(yp, 1);
                yp += __shfl_xor(yp, 2);
                if (sub == 0) yg[(size_t)(s*64+l)*256 + d] = yp;
            }
        }
        seq_barrier(slotbase + 2*4);   // S3: y visible within seq

        // ---- gate: g = (y + u*Dsk) * silu(z)  (u still in bufA) ----
        {
            int d = t & 255, half = t >> 8;
            float Dsk = D_skip[layer*256 + d];
            #pragma unroll
            for (int q = 0; q < 2; ++q) {
                int rloc = half*2 + q; int r = r0 + rloc;
                float z = xz[(size_t)r*512 + 256 + d];
                float yv = yg[(size_t)r*256 + d] + bufA[rloc][d]*Dsk;
                bufG[rloc][d] = yv * silu_f(z);
            }
        }
        __syncthreads();

        // ---- out-GEMM, K split 4 ways, LDS reduce ----
        {
            const int cc = t & 127, kc = t >> 7;
            const float* w = out_proj_w + ((size_t)layer*128 + cc)*256 + kc*64;
            float p0=0.f, p1=0.f, p2=0.f, p3=0.f;
            #pragma unroll
            for (int k4 = 0; k4 < 16; ++k4) {
                float4 wv = *(const float4*)&w[k4*4];
                p0 += dot4(*(const float4*)&bufG[0][kc*64 + k4*4], wv);
                p1 += dot4(*(const float4*)&bufG[1][kc*64 + k4*4], wv);
                p2 += dot4(*(const float4*)&bufG[2][kc*64 + k4*4], wv);
                p3 += dot4(*(const float4*)&bufG[3][kc*64 + k4*4], wv);
            }
            pOut[kc][0][cc] = p0;  pOut[kc][1][cc] = p1;
            pOut[kc][2][cc] = p2;  pOut[kc][3][cc] = p3;
        }
        __syncthreads();
        resid += pOut[0][h][c] + pOut[1][h][c] + pOut[2][h][c] + pOut[3][h][c];
        __syncthreads();
    }

    // ===================== final: row 63 of each seq =====================
    if (t == 0) anyv = 0;
    __syncthreads();
    if (rb == 15) {
        if (t < 64 && mask[s*4096 + t] != 0) anyv = 1;   // benign race
        float sq = wave_red_sum(resid*resid);
        if ((t & 63) == 0) part[wave] = sq;
    }
    __syncthreads();
    if (rb == 15 && h == 3) {
        float sr = part[6] + part[7];
        float sc = rsqrtf(sr*(1.0f/128.0f) + 1e-5f);
        float o  = resid * sc * norm_f_w[c];
        out[s*128 + c] = anyv ? o : 0.f;
    }
}

// ---------------------------------------------------------------------------
extern "C" void kernel_launch(void* const* d_in, const int* in_sizes, int n_in,
                              void* d_out, int out_size, void* d_ws, size_t ws_size,
                              hipStream_t stream) {
    (void)in_sizes; (void)n_in; (void)out_size; (void)ws_size;
    const float* mha_in     = (const float*)d_in[0];
    const int*   mask       = (const int*)  d_in[1];
    const float* mlp_w1     = (const float*)d_in[2];
    const float* mlp_b1     = (const float*)d_in[3];
    const float* mlp_w2     = (const float*)d_in[4];
    const float* mlp_b2     = (const float*)d_in[5];
    const float* in_proj_w  = (const float*)d_in[6];
    const float* conv_w     = (const float*)d_in[7];
    const float* conv_b     = (const float*)d_in[8];
    const float* x_proj_w   = (const float*)d_in[9];
    const float* dt_proj_w  = (const float*)d_in[10];
    const float* dt_proj_b  = (const float*)d_in[11];
    const float* A_log      = (const float*)d_in[12];
    const float* D_skip     = (const float*)d_in[13];
    const float* out_proj_w = (const float*)d_in[14];
    const float* blk_norm_w = (const float*)d_in[15];
    const float* norm_f_w   = (const float*)d_in[16];
    float* ws  = (float*)d_ws;
    float* out = (float*)d_out;

    // zero the barrier epoch counters (graph-capture-safe)
    hipMemsetAsync(d_ws, 0, 256, stream);

    void* args[] = {
        (void*)&mha_in, (void*)&mask, (void*)&mlp_w1, (void*)&mlp_b1,
        (void*)&mlp_w2, (void*)&mlp_b2, (void*)&in_proj_w, (void*)&conv_w,
        (void*)&conv_b, (void*)&x_proj_w, (void*)&dt_proj_w, (void*)&dt_proj_b,
        (void*)&A_log, (void*)&D_skip, (void*)&out_proj_w, (void*)&blk_norm_w,
        (void*)&norm_f_w, (void*)&ws, (void*)&out
    };
    hipLaunchCooperativeKernel((void*)fused_kernel, dim3(NWG), dim3(NTHR),
                               args, 0, stream);
}

// Round 4
// 286.806 us; speedup vs baseline: 5.3208x; 1.0142x over previous
//
#include <hip/hip_runtime.h>
#include <math.h>

#define NWG  64
#define NTHR 512

// ws layout (floats). First 512 floats = barrier flag slots (uint), host-zeroed:
//   S1 (per-wg xz handshake): slot (layer*4+s)*16 + rb          -> 0..255
//   S2 (per-seq full):        slot 256 + layer*4 + s            -> 256..271
//   S3 (per-seq full):        slot 272 + layer*4 + s            -> 272..287
#define WS_XZ 512                   // 256 x 512
#define WS_DT (WS_XZ + 131072)      // 256 x 256
#define WS_DU (WS_DT + 65536)       // 256 x 256  (du = dt*u)
#define WS_BC (WS_DU + 65536)       // 256 x 32
#define WS_Y  (WS_BC + 8192)        // 256 x 256

__device__ __forceinline__ float silu_f(float v) { return v / (1.0f + __expf(-v)); }
__device__ __forceinline__ float dot4(float4 a, float4 b) {
    return a.x*b.x + a.y*b.y + a.z*b.z + a.w*b.w;
}
__device__ __forceinline__ float wave_red_sum(float v) {
    v += __shfl_xor(v, 1);  v += __shfl_xor(v, 2);  v += __shfl_xor(v, 4);
    v += __shfl_xor(v, 8);  v += __shfl_xor(v, 16); v += __shfl_xor(v, 32);
    return v;
}
// Agent-coherent scalar load (global_load ... sc1): reads the coherence point,
// bypassing possibly-stale local L1/L2 — NO cache-wide invalidate.
__device__ __forceinline__ float aload(const float* p) {
    return __hip_atomic_load(p, __ATOMIC_RELAXED, __HIP_MEMORY_SCOPE_AGENT);
}

// Full per-seq barrier (16 wgs). Arrive = RELEASE fetch_add (waitcnt + wbl2,
// writes back dirty lines, no invalidate). Spin = RELAXED loads (no buffer_inv).
// Consumers read cross-wg data with aload(), so no acquire fence is needed.
__device__ __forceinline__ void seq_barrier(unsigned* slot) {
    __syncthreads();
    if (threadIdx.x == 0) {
        __hip_atomic_fetch_add(slot, 1u, __ATOMIC_RELEASE, __HIP_MEMORY_SCOPE_AGENT);
        while (__hip_atomic_load(slot, __ATOMIC_RELAXED, __HIP_MEMORY_SCOPE_AGENT) < 16u)
            __builtin_amdgcn_s_sleep(1);
    }
    __syncthreads();
}

// 64 wgs x 512 threads, cooperative (co-residency for the spin barriers).
// seq = wg & 3, row-block rb = wg >> 2 : owns rows l0..l0+3 (l0 = rb*4).
// Register residual: thread t owns (row h = t>>7, col c = t&127).
__global__ __launch_bounds__(NTHR) void fused_kernel(
    const float* __restrict__ mha_in, const int* __restrict__ mask,
    const float* __restrict__ mlp_w1, const float* __restrict__ mlp_b1,
    const float* __restrict__ mlp_w2, const float* __restrict__ mlp_b2,
    const float* __restrict__ in_proj_w, const float* __restrict__ conv_w,
    const float* __restrict__ conv_b, const float* __restrict__ x_proj_w,
    const float* __restrict__ dt_proj_w, const float* __restrict__ dt_proj_b,
    const float* __restrict__ A_log, const float* __restrict__ D_skip,
    const float* __restrict__ out_proj_w, const float* __restrict__ blk_norm_w,
    const float* __restrict__ norm_f_w,
    float* __restrict__ ws, float* __restrict__ out)
{
    const int wg = blockIdx.x;
    const int t  = threadIdx.x;
    const int s  = wg & 3;           // sequence
    const int rb = wg >> 2;          // row-block within seq (0..15)
    const int l0 = rb * 4;           // first owned local row
    const int r0 = s*64 + l0;        // first owned global row
    const int d0 = rb * 16;          // scan channel base
    const int h  = t >> 7;           // owned row 0..3
    const int c  = t & 127;          // owned col
    const int wave = t >> 6;

    unsigned* bar = (unsigned*)ws;
    float* xz  = ws + WS_XZ;
    float* dtg = ws + WS_DT;
    float* dug = ws + WS_DU;
    float* bcg = ws + WS_BC;
    float* yg  = ws + WS_Y;

    __shared__ float bufA[4][256];   // h1 / u (kept live through gate)
    __shared__ float bufG[4][256];   // g = (y + u*Dsk)*silu(z)
    __shared__ float bufB[4][128];   // x / hn
    __shared__ float xdS[4][40];
    __shared__ float sdt[64][16];    // staged dt   [l][ch]
    __shared__ float sdu[64][16];    // staged dt*u [l][ch]
    __shared__ float sbc[64][32];    // staged B,C  [l][0..15=B,16..31=C]
    __shared__ float pOut[4][4][128];
    __shared__ float part[8];
    __shared__ int   anyv;

    float resid;

    // ===================== MLP preamble (row-local) =====================
    bufB[h][c] = mha_in[(size_t)s*524288 + (size_t)(l0 + h)*128 + c];
    __syncthreads();
    {
        const float* w = mlp_w1 + (size_t)c * 128;
        float acc = 0.f;
        #pragma unroll 8
        for (int k4 = 0; k4 < 32; ++k4)
            acc += dot4(*(const float4*)&bufB[h][k4*4], *(const float4*)&w[k4*4]);
        float v = acc + mlp_b1[c];
        v = 0.5f*v*(1.0f + erff(v*0.70710678118f));
        bufA[h][c] = v;
    }
    __syncthreads();
    {
        const float* w = mlp_w2 + (size_t)c * 128;
        float acc = 0.f;
        #pragma unroll 8
        for (int k4 = 0; k4 < 32; ++k4)
            acc += dot4(*(const float4*)&bufA[h][k4*4], *(const float4*)&w[k4*4]);
        resid = acc + mlp_b2[c];
    }
    __syncthreads();

    // ===================== layer loop =====================
    for (int layer = 0; layer < 4; ++layer) {
        unsigned* s1slot = bar + (layer*4 + s)*16;
        unsigned* s2slot = bar + 256 + layer*4 + s;
        unsigned* s3slot = bar + 272 + layer*4 + s;

        // ---- rmsnorm(resid) -> bufB (hn) ----
        {
            float sq = wave_red_sum(resid*resid);
            if ((t & 63) == 0) part[wave] = sq;
        }
        __syncthreads();
        {
            float sr = part[h*2] + part[h*2 + 1];
            float sc = rsqrtf(sr*(1.0f/128.0f) + 1e-5f);
            bufB[h][c] = resid * sc * blk_norm_w[layer*128 + c];
        }
        __syncthreads();

        // ---- in-GEMM: xz[r0..r0+3][j=t], K=128, hn broadcast from LDS ----
        {
            const float* w = in_proj_w + ((size_t)layer*512 + t)*128;
            float a0=0.f, a1=0.f, a2=0.f, a3=0.f;
            #pragma unroll 8
            for (int k4 = 0; k4 < 32; ++k4) {
                float4 wv = *(const float4*)&w[k4*4];
                a0 += dot4(*(const float4*)&bufB[0][k4*4], wv);
                a1 += dot4(*(const float4*)&bufB[1][k4*4], wv);
                a2 += dot4(*(const float4*)&bufB[2][k4*4], wv);
                a3 += dot4(*(const float4*)&bufB[3][k4*4], wv);
            }
            xz[(size_t)(r0+0)*512 + t] = a0;
            xz[(size_t)(r0+1)*512 + t] = a1;
            xz[(size_t)(r0+2)*512 + t] = a2;
            xz[(size_t)(r0+3)*512 + t] = a3;
        }
        // ---- S1: neighbor handshake (conv needs only wg rb-1's last 3 rows) ----
        __syncthreads();
        if (t == 0) {
            __hip_atomic_fetch_add(s1slot + rb, 1u, __ATOMIC_RELEASE, __HIP_MEMORY_SCOPE_AGENT);
            if (rb > 0) {
                while (__hip_atomic_load(s1slot + rb - 1, __ATOMIC_RELAXED, __HIP_MEMORY_SCOPE_AGENT) == 0u)
                    __builtin_amdgcn_s_sleep(1);
            }
        }
        __syncthreads();

        // ---- conv + silu -> u in bufA (halo rows via agent-coherent loads) ----
        {
            int d = t & 255, half = t >> 8;           // 2 rows per thread
            int la = l0 + half*2;
            int rbase = s*64;
            float x0 = (la-3 >= 0) ? aload(&xz[(size_t)(rbase+la-3)*512 + d]) : 0.f;
            float x1 = (la-2 >= 0) ? aload(&xz[(size_t)(rbase+la-2)*512 + d]) : 0.f;
            float x2 = (la-1 >= 0) ? aload(&xz[(size_t)(rbase+la-1)*512 + d]) : 0.f;
            float x3 = xz[(size_t)(rbase+la  )*512 + d];   // own row
            float x4 = xz[(size_t)(rbase+la+1)*512 + d];   // own row
            float4 cw = *(const float4*)&conv_w[((size_t)layer*256 + d)*4];
            float cb = conv_b[layer*256 + d];
            bufA[half*2  ][d] = silu_f(cb + cw.x*x0 + cw.y*x1 + cw.z*x2 + cw.w*x3);
            bufA[half*2+1][d] = silu_f(cb + cw.x*x1 + cw.y*x2 + cw.z*x3 + cw.w*x4);
        }
        __syncthreads();

        // ---- xproj: xdbl[4][40], K=256 from LDS ----
        if (t < 160) {
            int rq = t & 3, jx = t >> 2;
            const float* xw = x_proj_w + ((size_t)layer*40 + jx)*256;
            float acc = 0.f;
            #pragma unroll 8
            for (int k4 = 0; k4 < 64; ++k4)
                acc += dot4(*(const float4*)&bufA[rq][k4*4], *(const float4*)&xw[k4*4]);
            xdS[rq][jx] = acc;
        }
        __syncthreads();

        // ---- dt = softplus(...) ; write dt and du = dt*u ----
        {
            int d = t & 255, half = t >> 8;
            const float* dw = dt_proj_w + ((size_t)layer*256 + d)*8;
            float4 wa = *(const float4*)&dw[0];
            float4 wb = *(const float4*)&dw[4];
            float b = dt_proj_b[layer*256 + d];
            #pragma unroll
            for (int q = 0; q < 2; ++q) {
                int rloc = half*2 + q;
                float4 xa = *(const float4*)&xdS[rloc][0];
                float4 xb = *(const float4*)&xdS[rloc][4];
                float pre = b + dot4(xa, wa) + dot4(xb, wb);
                float sp = (pre > 20.f) ? pre : log1pf(__expf(pre));
                dtg[(size_t)(r0+rloc)*256 + d] = sp;
                dug[(size_t)(r0+rloc)*256 + d] = sp * bufA[rloc][d];
            }
        }
        // ---- pack B,C ----
        if (t < 128) {
            int r = t >> 5, j = t & 31;
            bcg[(size_t)(r0+r)*32 + j] = xdS[r][8 + j];
        }
        seq_barrier(s2slot);   // S2: dt, du, B, C visible within seq

        // ---- stage scan inputs (agent-coherent) into LDS ----
        if (t < 256) {
            int l = t >> 2, q = t & 3;
            const float* p = &dtg[(size_t)(s*64+l)*256 + d0 + q*4];
            float4 v; v.x = aload(p); v.y = aload(p+1); v.z = aload(p+2); v.w = aload(p+3);
            *(float4*)&sdt[l][q*4] = v;
        } else {
            int tt = t - 256; int l = tt >> 2, q = tt & 3;
            const float* p = &dug[(size_t)(s*64+l)*256 + d0 + q*4];
            float4 v; v.x = aload(p); v.y = aload(p+1); v.z = aload(p+2); v.w = aload(p+3);
            *(float4*)&sdu[l][q*4] = v;
        }
        {
            int l = t >> 3, q = t & 7;
            const float* p = &bcg[(size_t)(s*64+l)*32 + q*4];
            float4 v; v.x = aload(p); v.y = aload(p+1); v.z = aload(p+2); v.w = aload(p+3);
            *(float4*)&sbc[l][q*4] = v;
        }
        __syncthreads();

        // ---- selective scan from LDS: 16 channels x 4 sub-lanes ----
        if (t < 64) {
            const int dloc = t >> 2, sub = t & 3, d = d0 + dloc;
            const float* Ab = A_log + ((size_t)layer*256 + d)*16 + sub*4;
            float A0 = -__expf(Ab[0]), A1 = -__expf(Ab[1]);
            float A2 = -__expf(Ab[2]), A3 = -__expf(Ab[3]);
            float h0 = 0.f, h1v = 0.f, h2v = 0.f, h3v = 0.f;
            #pragma unroll 4
            for (int l = 0; l < 64; ++l) {
                float dtv = sdt[l][dloc];
                float duv = sdu[l][dloc];
                float4 B4 = *(const float4*)&sbc[l][sub*4];
                float4 C4 = *(const float4*)&sbc[l][16 + sub*4];
                float dA, yp;
                dA = __expf(dtv*A0); h0  = dA*h0  + duv*B4.x; yp  = h0 *C4.x;
                dA = __expf(dtv*A1); h1v = dA*h1v + duv*B4.y; yp += h1v*C4.y;
                dA = __expf(dtv*A2); h2v = dA*h2v + duv*B4.z; yp += h2v*C4.z;
                dA = __expf(dtv*A3); h3v = dA*h3v + duv*B4.w; yp += h3v*C4.w;
                yp += __shfl_xor(yp, 1);
                yp += __shfl_xor(yp, 2);
                if (sub == 0) yg[(size_t)(s*64+l)*256 + d] = yp;
            }
        }
        seq_barrier(s3slot);   // S3: y visible within seq

        // ---- gate: g = (y + u*Dsk) * silu(z)  (u in bufA, y cross-wg) ----
        {
            int d = t & 255, half = t >> 8;
            float Dsk = D_skip[layer*256 + d];
            #pragma unroll
            for (int q = 0; q < 2; ++q) {
                int rloc = half*2 + q; int r = r0 + rloc;
                float z = xz[(size_t)r*512 + 256 + d];          // own row
                float yv = aload(&yg[(size_t)r*256 + d]) + bufA[rloc][d]*Dsk;
                bufG[rloc][d] = yv * silu_f(z);
            }
        }
        __syncthreads();

        // ---- out-GEMM, K split 4 ways, LDS reduce ----
        {
            const int cc = t & 127, kc = t >> 7;
            const float* w = out_proj_w + ((size_t)layer*128 + cc)*256 + kc*64;
            float p0=0.f, p1=0.f, p2=0.f, p3=0.f;
            #pragma unroll
            for (int k4 = 0; k4 < 16; ++k4) {
                float4 wv = *(const float4*)&w[k4*4];
                p0 += dot4(*(const float4*)&bufG[0][kc*64 + k4*4], wv);
                p1 += dot4(*(const float4*)&bufG[1][kc*64 + k4*4], wv);
                p2 += dot4(*(const float4*)&bufG[2][kc*64 + k4*4], wv);
                p3 += dot4(*(const float4*)&bufG[3][kc*64 + k4*4], wv);
            }
            pOut[kc][0][cc] = p0;  pOut[kc][1][cc] = p1;
            pOut[kc][2][cc] = p2;  pOut[kc][3][cc] = p3;
        }
        __syncthreads();
        resid += pOut[0][h][c] + pOut[1][h][c] + pOut[2][h][c] + pOut[3][h][c];
        __syncthreads();
    }

    // ===================== final: row 63 of each seq =====================
    if (t == 0) anyv = 0;
    __syncthreads();
    if (rb == 15) {
        if (t < 64 && mask[s*4096 + t] != 0) anyv = 1;   // benign race
        float sq = wave_red_sum(resid*resid);
        if ((t & 63) == 0) part[wave] = sq;
    }
    __syncthreads();
    if (rb == 15 && h == 3) {
        float sr = part[6] + part[7];
        float sc = rsqrtf(sr*(1.0f/128.0f) + 1e-5f);
        float o  = resid * sc * norm_f_w[c];
        out[s*128 + c] = anyv ? o : 0.f;
    }
}

// ---------------------------------------------------------------------------
extern "C" void kernel_launch(void* const* d_in, const int* in_sizes, int n_in,
                              void* d_out, int out_size, void* d_ws, size_t ws_size,
                              hipStream_t stream) {
    (void)in_sizes; (void)n_in; (void)out_size; (void)ws_size;
    const float* mha_in     = (const float*)d_in[0];
    const int*   mask       = (const int*)  d_in[1];
    const float* mlp_w1     = (const float*)d_in[2];
    const float* mlp_b1     = (const float*)d_in[3];
    const float* mlp_w2     = (const float*)d_in[4];
    const float* mlp_b2     = (const float*)d_in[5];
    const float* in_proj_w  = (const float*)d_in[6];
    const float* conv_w     = (const float*)d_in[7];
    const float* conv_b     = (const float*)d_in[8];
    const float* x_proj_w   = (const float*)d_in[9];
    const float* dt_proj_w  = (const float*)d_in[10];
    const float* dt_proj_b  = (const float*)d_in[11];
    const float* A_log      = (const float*)d_in[12];
    const float* D_skip     = (const float*)d_in[13];
    const float* out_proj_w = (const float*)d_in[14];
    const float* blk_norm_w = (const float*)d_in[15];
    const float* norm_f_w   = (const float*)d_in[16];
    float* ws  = (float*)d_ws;
    float* out = (float*)d_out;

    // zero the barrier flag slots (graph-capture-safe)
    hipMemsetAsync(d_ws, 0, 2048, stream);

    void* args[] = {
        (void*)&mha_in, (void*)&mask, (void*)&mlp_w1, (void*)&mlp_b1,
        (void*)&mlp_w2, (void*)&mlp_b2, (void*)&in_proj_w, (void*)&conv_w,
        (void*)&conv_b, (void*)&x_proj_w, (void*)&dt_proj_w, (void*)&dt_proj_b,
        (void*)&A_log, (void*)&D_skip, (void*)&out_proj_w, (void*)&blk_norm_w,
        (void*)&norm_f_w, (void*)&ws, (void*)&out
    };
    hipLaunchCooperativeKernel((void*)fused_kernel, dim3(NWG), dim3(NTHR),
                               args, 0, stream);
}

// Round 5
// 284.285 us; speedup vs baseline: 5.3679x; 1.0089x over previous
//
#include <hip/hip_runtime.h>
#include <math.h>

#define NWG  64
#define NTHR 512

// ws layout (floats). First 512 floats = barrier flag slots (uint), zeroed by
// the hipMemsetAsync below:
//   S1 (per-wg xg handshake): slot (layer*4+s)*16 + rb          -> 0..255
//   S2 (per-seq full):        slot 256 + layer*4 + s            -> 256..271
//   S3 (per-seq full):        slot 272 + layer*4 + s            -> 272..287
#define WS_XG 512                   // 256 rows x 256 (x-half of in_proj output)
#define WS_DT (WS_XG + 65536)       // 256 x 256
#define WS_DU (WS_DT + 65536)       // 256 x 256  (du = dt*u)
#define WS_BC (WS_DU + 65536)       // 256 x 32
#define WS_Y  (WS_BC + 8192)        // 256 x 256

__device__ __forceinline__ float silu_f(float v) { return v / (1.0f + __expf(-v)); }
__device__ __forceinline__ float dot4(float4 a, float4 b) {
    return a.x*b.x + a.y*b.y + a.z*b.z + a.w*b.w;
}
__device__ __forceinline__ float wave_red_sum(float v) {
    v += __shfl_xor(v, 1);  v += __shfl_xor(v, 2);  v += __shfl_xor(v, 4);
    v += __shfl_xor(v, 8);  v += __shfl_xor(v, 16); v += __shfl_xor(v, 32);
    return v;
}
// Agent-coherent scalar load: reads the coherence point, bypassing possibly
// stale local L1/L2. No cache-wide invalidate.
__device__ __forceinline__ float aload(const float* p) {
    return __hip_atomic_load(p, __ATOMIC_RELAXED, __HIP_MEMORY_SCOPE_AGENT);
}

// Full per-seq barrier (16 wgs). Arrive = RELEASE fetch_add (drains stores +
// L2 writeback, no invalidate). Spin = RELAXED loads (no buffer_inv).
// Consumers read cross-wg data with aload(), so no acquire fence is needed.
__device__ __forceinline__ void seq_barrier(unsigned* slot) {
    __syncthreads();
    if (threadIdx.x == 0) {
        __hip_atomic_fetch_add(slot, 1u, __ATOMIC_RELEASE, __HIP_MEMORY_SCOPE_AGENT);
        while (__hip_atomic_load(slot, __ATOMIC_RELAXED, __HIP_MEMORY_SCOPE_AGENT) < 16u)
            __builtin_amdgcn_s_sleep(1);
    }
    __syncthreads();
}

// 64 wgs x 512 threads, REGULAR launch. Co-residency by capacity: grid 64 <=
// 256 CUs, 1 wg/CU worth of resources (512 thr, ~44KB LDS, <=128 VGPR), so all
// wgs are resident immediately and the spin barriers cannot deadlock.
// seq = wg & 3, row-block rb = wg >> 2 : owns rows l0..l0+3 (l0 = rb*4).
// Register residual: thread t owns (row h = t>>7, col c = t&127).
__global__ __launch_bounds__(NTHR) void fused_kernel(
    const float* __restrict__ mha_in, const int* __restrict__ mask,
    const float* __restrict__ mlp_w1, const float* __restrict__ mlp_b1,
    const float* __restrict__ mlp_w2, const float* __restrict__ mlp_b2,
    const float* __restrict__ in_proj_w, const float* __restrict__ conv_w,
    const float* __restrict__ conv_b, const float* __restrict__ x_proj_w,
    const float* __restrict__ dt_proj_w, const float* __restrict__ dt_proj_b,
    const float* __restrict__ A_log, const float* __restrict__ D_skip,
    const float* __restrict__ out_proj_w, const float* __restrict__ blk_norm_w,
    const float* __restrict__ norm_f_w,
    float* __restrict__ ws, float* __restrict__ out)
{
    const int wg = blockIdx.x;
    const int t  = threadIdx.x;
    const int s  = wg & 3;           // sequence
    const int rb = wg >> 2;          // row-block within seq (0..15)
    const int l0 = rb * 4;           // first owned local row
    const int r0 = s*64 + l0;        // first owned global row
    const int d0 = rb * 16;          // scan channel base
    const int h  = t >> 7;           // owned row 0..3
    const int c  = t & 127;          // owned col
    const int wave = t >> 6;

    unsigned* bar = (unsigned*)ws;
    float* xg  = ws + WS_XG;
    float* dtg = ws + WS_DT;
    float* dug = ws + WS_DU;
    float* bcg = ws + WS_BC;
    float* yg  = ws + WS_Y;

    __shared__ float bufX[4][256];   // x (conv input, own rows)
    __shared__ float bufZ[4][256];   // z (computed during scan window)
    __shared__ float bufA[4][256];   // h1 / u (kept live through gate)
    __shared__ float bufG[4][256];   // g = (y + u*Dsk)*silu(z)
    __shared__ float bufB[4][128];   // x_in / hn
    __shared__ float xdS[4][40];
    __shared__ float sdt[64][17];    // staged dt   [l][ch]  (+1 pad: banks)
    __shared__ float sdu[64][17];    // staged dt*u [l][ch]
    __shared__ float sbc[64][33];    // staged B,C  [l][0..15=B,16..31=C]
    __shared__ float pOut[4][4][128];
    __shared__ float part[8];
    __shared__ int   anyv;

    float resid;

    // ===================== MLP preamble (row-local) =====================
    bufB[h][c] = mha_in[(size_t)s*524288 + (size_t)(l0 + h)*128 + c];
    __syncthreads();
    {
        const float* w = mlp_w1 + (size_t)c * 128;
        float acc = 0.f;
        #pragma unroll 8
        for (int k4 = 0; k4 < 32; ++k4)
            acc += dot4(*(const float4*)&bufB[h][k4*4], *(const float4*)&w[k4*4]);
        float v = acc + mlp_b1[c];
        v = 0.5f*v*(1.0f + erff(v*0.70710678118f));
        bufA[h][c] = v;
    }
    __syncthreads();
    {
        const float* w = mlp_w2 + (size_t)c * 128;
        float acc = 0.f;
        #pragma unroll 8
        for (int k4 = 0; k4 < 32; ++k4)
            acc += dot4(*(const float4*)&bufA[h][k4*4], *(const float4*)&w[k4*4]);
        resid = acc + mlp_b2[c];
    }
    __syncthreads();

    // ===================== layer loop =====================
    for (int layer = 0; layer < 4; ++layer) {
        unsigned* s1slot = bar + (layer*4 + s)*16;
        unsigned* s2slot = bar + 256 + layer*4 + s;
        unsigned* s3slot = bar + 272 + layer*4 + s;

        // ---- rmsnorm(resid) -> bufB (hn) ----
        {
            float sq = wave_red_sum(resid*resid);
            if ((t & 63) == 0) part[wave] = sq;
        }
        __syncthreads();
        {
            float sr = part[h*2] + part[h*2 + 1];
            float sc = rsqrtf(sr*(1.0f/128.0f) + 1e-5f);
            bufB[h][c] = resid * sc * blk_norm_w[layer*128 + c];
        }
        __syncthreads();

        // ---- in-GEMM x-half: cols 0..255, 2 rows/thread -> bufX + xg ----
        {
            const int d = t & 255, hp = t >> 8;      // rows hp*2, hp*2+1
            const float* w = in_proj_w + ((size_t)layer*512 + d)*128;
            float a0 = 0.f, a1 = 0.f;
            #pragma unroll 8
            for (int k4 = 0; k4 < 32; ++k4) {
                float4 wv = *(const float4*)&w[k4*4];
                a0 += dot4(*(const float4*)&bufB[hp*2  ][k4*4], wv);
                a1 += dot4(*(const float4*)&bufB[hp*2+1][k4*4], wv);
            }
            bufX[hp*2  ][d] = a0;
            bufX[hp*2+1][d] = a1;
            xg[(size_t)(r0 + hp*2    )*256 + d] = a0;   // halo for wg rb+1
            xg[(size_t)(r0 + hp*2 + 1)*256 + d] = a1;
        }
        // ---- S1: neighbor handshake (conv needs wg rb-1's last 3 rows) ----
        __syncthreads();
        if (t == 0) {
            __hip_atomic_fetch_add(s1slot + rb, 1u, __ATOMIC_RELEASE, __HIP_MEMORY_SCOPE_AGENT);
            if (rb > 0) {
                while (__hip_atomic_load(s1slot + rb - 1, __ATOMIC_RELAXED, __HIP_MEMORY_SCOPE_AGENT) == 0u)
                    __builtin_amdgcn_s_sleep(1);
            }
        }
        __syncthreads();

        // ---- conv + silu -> u in bufA (own rows from LDS, halo via aload) --
        {
            int d = t & 255, half = t >> 8;           // 2 rows per thread
            int rbase = s*64;
            float4 cw = *(const float4*)&conv_w[((size_t)layer*256 + d)*4];
            float cb = conv_b[layer*256 + d];
            if (half == 0) {
                float x0 = (l0-3 >= 0) ? aload(&xg[(size_t)(rbase+l0-3)*256 + d]) : 0.f;
                float x1 = (l0-2 >= 0) ? aload(&xg[(size_t)(rbase+l0-2)*256 + d]) : 0.f;
                float x2 = (l0-1 >= 0) ? aload(&xg[(size_t)(rbase+l0-1)*256 + d]) : 0.f;
                float x3 = bufX[0][d];
                float x4 = bufX[1][d];
                bufA[0][d] = silu_f(cb + cw.x*x0 + cw.y*x1 + cw.z*x2 + cw.w*x3);
                bufA[1][d] = silu_f(cb + cw.x*x1 + cw.y*x2 + cw.z*x3 + cw.w*x4);
            } else {
                float x0 = (l0-1 >= 0) ? aload(&xg[(size_t)(rbase+l0-1)*256 + d]) : 0.f;
                float x1 = bufX[0][d];
                float x2 = bufX[1][d];
                float x3 = bufX[2][d];
                float x4 = bufX[3][d];
                bufA[2][d] = silu_f(cb + cw.x*x0 + cw.y*x1 + cw.z*x2 + cw.w*x3);
                bufA[3][d] = silu_f(cb + cw.x*x1 + cw.y*x2 + cw.z*x3 + cw.w*x4);
            }
        }
        __syncthreads();

        // ---- xproj: xdbl[4][40], K=256 from LDS ----
        if (t < 160) {
            int rq = t & 3, jx = t >> 2;
            const float* xw = x_proj_w + ((size_t)layer*40 + jx)*256;
            float acc = 0.f;
            #pragma unroll 8
            for (int k4 = 0; k4 < 64; ++k4)
                acc += dot4(*(const float4*)&bufA[rq][k4*4], *(const float4*)&xw[k4*4]);
            xdS[rq][jx] = acc;
        }
        __syncthreads();

        // ---- dt = softplus(...) ; write dt and du = dt*u ----
        {
            int d = t & 255, half = t >> 8;
            const float* dw = dt_proj_w + ((size_t)layer*256 + d)*8;
            float4 wa = *(const float4*)&dw[0];
            float4 wb = *(const float4*)&dw[4];
            float b = dt_proj_b[layer*256 + d];
            #pragma unroll
            for (int q = 0; q < 2; ++q) {
                int rloc = half*2 + q;
                float4 xa = *(const float4*)&xdS[rloc][0];
                float4 xb = *(const float4*)&xdS[rloc][4];
                float pre = b + dot4(xa, wa) + dot4(xb, wb);
                float sp = (pre > 20.f) ? pre : log1pf(__expf(pre));
                dtg[(size_t)(r0+rloc)*256 + d] = sp;
                dug[(size_t)(r0+rloc)*256 + d] = sp * bufA[rloc][d];
            }
        }
        // ---- pack B,C ----
        if (t < 128) {
            int r = t >> 5, j = t & 31;
            bcg[(size_t)(r0+r)*32 + j] = xdS[r][8 + j];
        }
        seq_barrier(s2slot);   // S2: dt, du, B, C visible within seq

        // ---- scan window: wave0 stages+scans; waves 4-7 compute z-GEMM ----
        if (t < 64) {
            // stage row l = t of this seq's scan inputs (channels d0..d0+15)
            {
                const int l = t;
                const float* pd = dtg + (size_t)(s*64+l)*256 + d0;
                const float* pu = dug + (size_t)(s*64+l)*256 + d0;
                const float* pb = bcg + (size_t)(s*64+l)*32;
                #pragma unroll
                for (int i = 0; i < 16; ++i) sdt[l][i] = aload(pd + i);
                #pragma unroll
                for (int i = 0; i < 16; ++i) sdu[l][i] = aload(pu + i);
                #pragma unroll
                for (int i = 0; i < 32; ++i) sbc[l][i] = aload(pb + i);
            }
            // same-wave LDS RAW: compiler orders ds_write -> ds_read via lgkmcnt
            const int dloc = t >> 2, sub = t & 3, d = d0 + dloc;
            const float* Ab = A_log + ((size_t)layer*256 + d)*16 + sub*4;
            float A0 = -__expf(Ab[0]), A1 = -__expf(Ab[1]);
            float A2 = -__expf(Ab[2]), A3 = -__expf(Ab[3]);
            float h0 = 0.f, h1v = 0.f, h2v = 0.f, h3v = 0.f;
            #pragma unroll 4
            for (int l = 0; l < 64; ++l) {
                float dtv = sdt[l][dloc];
                float duv = sdu[l][dloc];
                float4 B4, C4;
                B4.x = sbc[l][sub*4];      B4.y = sbc[l][sub*4+1];
                B4.z = sbc[l][sub*4+2];    B4.w = sbc[l][sub*4+3];
                C4.x = sbc[l][16+sub*4];   C4.y = sbc[l][16+sub*4+1];
                C4.z = sbc[l][16+sub*4+2]; C4.w = sbc[l][16+sub*4+3];
                float dA, yp;
                dA = __expf(dtv*A0); h0  = dA*h0  + duv*B4.x; yp  = h0 *C4.x;
                dA = __expf(dtv*A1); h1v = dA*h1v + duv*B4.y; yp += h1v*C4.y;
                dA = __expf(dtv*A2); h2v = dA*h2v + duv*B4.z; yp += h2v*C4.z;
                dA = __expf(dtv*A3); h3v = dA*h3v + duv*B4.w; yp += h3v*C4.w;
                yp += __shfl_xor(yp, 1);
                yp += __shfl_xor(yp, 2);
                if (sub == 0) yg[(size_t)(s*64+l)*256 + d] = yp;
            }
        } else if (t >= 256) {
            // in-GEMM z-half: col dz, 4 rows, hn still in bufB
            const int dz = t - 256;
            const float* w = in_proj_w + ((size_t)layer*512 + 256 + dz)*128;
            float a0=0.f, a1=0.f, a2=0.f, a3=0.f;
            #pragma unroll 8
            for (int k4 = 0; k4 < 32; ++k4) {
                float4 wv = *(const float4*)&w[k4*4];
                a0 += dot4(*(const float4*)&bufB[0][k4*4], wv);
                a1 += dot4(*(const float4*)&bufB[1][k4*4], wv);
                a2 += dot4(*(const float4*)&bufB[2][k4*4], wv);
                a3 += dot4(*(const float4*)&bufB[3][k4*4], wv);
            }
            bufZ[0][dz] = a0;  bufZ[1][dz] = a1;
            bufZ[2][dz] = a2;  bufZ[3][dz] = a3;
        }
        seq_barrier(s3slot);   // S3: y visible within seq (+ bufZ via syncthreads)

        // ---- gate: g = (y + u*Dsk) * silu(z)  (u in bufA, z in bufZ) ----
        {
            int d = t & 255, half = t >> 8;
            float Dsk = D_skip[layer*256 + d];
            #pragma unroll
            for (int q = 0; q < 2; ++q) {
                int rloc = half*2 + q; int r = r0 + rloc;
                float z = bufZ[rloc][d];
                float yv = aload(&yg[(size_t)r*256 + d]) + bufA[rloc][d]*Dsk;
                bufG[rloc][d] = yv * silu_f(z);
            }
        }
        __syncthreads();

        // ---- out-GEMM, K split 4 ways, LDS reduce ----
        {
            const int cc = t & 127, kc = t >> 7;
            const float* w = out_proj_w + ((size_t)layer*128 + cc)*256 + kc*64;
            float p0=0.f, p1=0.f, p2=0.f, p3=0.f;
            #pragma unroll
            for (int k4 = 0; k4 < 16; ++k4) {
                float4 wv = *(const float4*)&w[k4*4];
                p0 += dot4(*(const float4*)&bufG[0][kc*64 + k4*4], wv);
                p1 += dot4(*(const float4*)&bufG[1][kc*64 + k4*4], wv);
                p2 += dot4(*(const float4*)&bufG[2][kc*64 + k4*4], wv);
                p3 += dot4(*(const float4*)&bufG[3][kc*64 + k4*4], wv);
            }
            pOut[kc][0][cc] = p0;  pOut[kc][1][cc] = p1;
            pOut[kc][2][cc] = p2;  pOut[kc][3][cc] = p3;
        }
        __syncthreads();
        resid += pOut[0][h][c] + pOut[1][h][c] + pOut[2][h][c] + pOut[3][h][c];
        __syncthreads();
    }

    // ===================== final: row 63 of each seq =====================
    if (t == 0) anyv = 0;
    __syncthreads();
    if (rb == 15) {
        if (t < 64 && mask[s*4096 + t] != 0) anyv = 1;   // benign race
        float sq = wave_red_sum(resid*resid);
        if ((t & 63) == 0) part[wave] = sq;
    }
    __syncthreads();
    if (rb == 15 && h == 3) {
        float sr = part[6] + part[7];
        float sc = rsqrtf(sr*(1.0f/128.0f) + 1e-5f);
        float o  = resid * sc * norm_f_w[c];
        out[s*128 + c] = anyv ? o : 0.f;
    }
}

// ---------------------------------------------------------------------------
extern "C" void kernel_launch(void* const* d_in, const int* in_sizes, int n_in,
                              void* d_out, int out_size, void* d_ws, size_t ws_size,
                              hipStream_t stream) {
    (void)in_sizes; (void)n_in; (void)out_size; (void)ws_size;
    const float* mha_in     = (const float*)d_in[0];
    const int*   mask       = (const int*)  d_in[1];
    const float* mlp_w1     = (const float*)d_in[2];
    const float* mlp_b1     = (const float*)d_in[3];
    const float* mlp_w2     = (const float*)d_in[4];
    const float* mlp_b2     = (const float*)d_in[5];
    const float* in_proj_w  = (const float*)d_in[6];
    const float* conv_w     = (const float*)d_in[7];
    const float* conv_b     = (const float*)d_in[8];
    const float* x_proj_w   = (const float*)d_in[9];
    const float* dt_proj_w  = (const float*)d_in[10];
    const float* dt_proj_b  = (const float*)d_in[11];
    const float* A_log      = (const float*)d_in[12];
    const float* D_skip     = (const float*)d_in[13];
    const float* out_proj_w = (const float*)d_in[14];
    const float* blk_norm_w = (const float*)d_in[15];
    const float* norm_f_w   = (const float*)d_in[16];
    float* ws  = (float*)d_ws;
    float* out = (float*)d_out;

    // zero the barrier flag slots (graph-capture-safe)
    hipMemsetAsync(d_ws, 0, 2048, stream);

    // Regular launch: 64 wgs <= 256 CUs with 1-wg/CU resources => all
    // co-resident; spin barriers are deadlock-free.
    fused_kernel<<<NWG, NTHR, 0, stream>>>(
        mha_in, mask, mlp_w1, mlp_b1, mlp_w2, mlp_b2,
        in_proj_w, conv_w, conv_b, x_proj_w, dt_proj_w, dt_proj_b,
        A_log, D_skip, out_proj_w, blk_norm_w, norm_f_w, ws, out);
}

// Round 7
// 253.922 us; speedup vs baseline: 6.0098x; 1.1196x over previous
//
#include <hip/hip_runtime.h>
#include <math.h>

#define NWG  64
#define NTHR 512

// ws layout (floats). First 512 floats = barrier flag slots (uint), zeroed by
// the hipMemsetAsync below:
//   S1 (per-wg xg handshake): slot (layer*4+s)*16 + rb          -> 0..255
//   S2 (per-seq full):        slot 256 + layer*4 + s            -> 256..271
//   S3 (per-seq full):        slot 272 + layer*4 + s            -> 272..287
#define WS_XG 512                   // 256 rows x 256 (x-half of in_proj output)
#define WS_DT (WS_XG + 65536)       // 256 x 256
#define WS_DU (WS_DT + 65536)       // 256 x 256  (du = dt*u)
#define WS_BC (WS_DU + 65536)       // 256 x 32
#define WS_Y  (WS_BC + 8192)        // 256 x 256

__device__ __forceinline__ float silu_f(float v) { return v / (1.0f + __expf(-v)); }
__device__ __forceinline__ float dot4(float4 a, float4 b) {
    return a.x*b.x + a.y*b.y + a.z*b.z + a.w*b.w;
}
__device__ __forceinline__ float wave_red_sum(float v) {
    v += __shfl_xor(v, 1);  v += __shfl_xor(v, 2);  v += __shfl_xor(v, 4);
    v += __shfl_xor(v, 8);  v += __shfl_xor(v, 16); v += __shfl_xor(v, 32);
    return v;
}
// Agent-coherent scalar load: reads the coherence point, bypassing possibly
// stale local L1/L2. No cache-wide invalidate.
__device__ __forceinline__ float aload(const float* p) {
    return __hip_atomic_load(p, __ATOMIC_RELAXED, __HIP_MEMORY_SCOPE_AGENT);
}

// Full per-seq barrier (16 wgs). Arrive = RELEASE fetch_add (drains stores +
// L2 writeback, no invalidate). Spin = RELAXED loads (no buffer_inv).
// Consumers read cross-wg data with aload(), so no acquire fence is needed.
__device__ __forceinline__ void seq_barrier(unsigned* slot) {
    __syncthreads();
    if (threadIdx.x == 0) {
        __hip_atomic_fetch_add(slot, 1u, __ATOMIC_RELEASE, __HIP_MEMORY_SCOPE_AGENT);
        while (__hip_atomic_load(slot, __ATOMIC_RELAXED, __HIP_MEMORY_SCOPE_AGENT) < 16u)
            __builtin_amdgcn_s_sleep(1);
    }
    __syncthreads();
}

// 64 wgs x 512 threads, REGULAR launch. Co-residency by capacity: grid 64 <=
// 256 CUs, 1 wg/CU worth of resources, so all wgs are resident immediately
// and the spin barriers cannot deadlock.
// __launch_bounds__(512,1): 1 wave/SIMD floor -> VGPR cap 256 (we run 1
// wg/CU; extra occupancy is useless, deep load pipelining is not).
// seq = wg & 3, row-block rb = wg >> 2 : owns rows l0..l0+3 (l0 = rb*4).
// Register residual: thread t owns (row h = t>>7, col c = t&127).
__global__ __launch_bounds__(NTHR, 1) void fused_kernel(
    const float* __restrict__ mha_in, const int* __restrict__ mask,
    const float* __restrict__ mlp_w1, const float* __restrict__ mlp_b1,
    const float* __restrict__ mlp_w2, const float* __restrict__ mlp_b2,
    const float* __restrict__ in_proj_w, const float* __restrict__ conv_w,
    const float* __restrict__ conv_b, const float* __restrict__ x_proj_w,
    const float* __restrict__ dt_proj_w, const float* __restrict__ dt_proj_b,
    const float* __restrict__ A_log, const float* __restrict__ D_skip,
    const float* __restrict__ out_proj_w, const float* __restrict__ blk_norm_w,
    const float* __restrict__ norm_f_w,
    float* __restrict__ ws, float* __restrict__ out)
{
    const int wg = blockIdx.x;
    const int t  = threadIdx.x;
    const int s  = wg & 3;           // sequence
    const int rb = wg >> 2;          // row-block within seq (0..15)
    const int l0 = rb * 4;           // first owned local row
    const int r0 = s*64 + l0;        // first owned global row
    const int d0 = rb * 16;          // scan channel base
    const int h  = t >> 7;           // owned row 0..3
    const int c  = t & 127;          // owned col
    const int wave = t >> 6;

    unsigned* bar = (unsigned*)ws;
    float* xg  = ws + WS_XG;
    float* dtg = ws + WS_DT;
    float* dug = ws + WS_DU;
    float* bcg = ws + WS_BC;
    float* yg  = ws + WS_Y;

    __shared__ float bufX[4][256];   // x (conv input, own rows)
    __shared__ float bufZ[4][256];   // z (computed during scan window)
    __shared__ float bufA[4][256];   // h1 / u (kept live through gate)
    __shared__ float bufG[4][256];   // g = (y + u*Dsk)*silu(z)
    __shared__ float bufB[4][128];   // x_in / hn
    __shared__ float xdS[4][40];
    __shared__ float sdt[64][17];    // staged dt   [l][ch]  (+1 pad: banks)
    __shared__ float sdu[64][17];    // staged dt*u [l][ch]
    __shared__ float sbc[64][33];    // staged B,C  [l][0..15=B,16..31=C]
    __shared__ float pOut[4][4][128];
    __shared__ float part[8];
    __shared__ int   anyv;

    float resid;

    // ===================== MLP preamble (row-local) =====================
    bufB[h][c] = mha_in[(size_t)s*524288 + (size_t)(l0 + h)*128 + c];
    __syncthreads();
    {
        const float* w = mlp_w1 + (size_t)c * 128;
        float acc = 0.f;
        #pragma unroll 16
        for (int k4 = 0; k4 < 32; ++k4)
            acc += dot4(*(const float4*)&bufB[h][k4*4], *(const float4*)&w[k4*4]);
        float v = acc + mlp_b1[c];
        v = 0.5f*v*(1.0f + erff(v*0.70710678118f));
        bufA[h][c] = v;
    }
    __syncthreads();
    {
        const float* w = mlp_w2 + (size_t)c * 128;
        float acc = 0.f;
        #pragma unroll 16
        for (int k4 = 0; k4 < 32; ++k4)
            acc += dot4(*(const float4*)&bufA[h][k4*4], *(const float4*)&w[k4*4]);
        resid = acc + mlp_b2[c];
    }
    __syncthreads();

    // ===================== layer loop =====================
    for (int layer = 0; layer < 4; ++layer) {
        unsigned* s1slot = bar + (layer*4 + s)*16;
        unsigned* s2slot = bar + 256 + layer*4 + s;
        unsigned* s3slot = bar + 272 + layer*4 + s;

        // ---- rmsnorm(resid) -> bufB (hn) ----
        {
            float sq = wave_red_sum(resid*resid);
            if ((t & 63) == 0) part[wave] = sq;
        }
        __syncthreads();
        {
            float sr = part[h*2] + part[h*2 + 1];
            float sc = rsqrtf(sr*(1.0f/128.0f) + 1e-5f);
            bufB[h][c] = resid * sc * blk_norm_w[layer*128 + c];
        }
        __syncthreads();

        // ---- in-GEMM x-half: cols 0..255, 2 rows/thread -> bufX + xg ----
        {
            const int d = t & 255, hp = t >> 8;      // rows hp*2, hp*2+1
            const float* w = in_proj_w + ((size_t)layer*512 + d)*128;
            float a0 = 0.f, a1 = 0.f;
            #pragma unroll 16
            for (int k4 = 0; k4 < 32; ++k4) {
                float4 wv = *(const float4*)&w[k4*4];
                a0 += dot4(*(const float4*)&bufB[hp*2  ][k4*4], wv);
                a1 += dot4(*(const float4*)&bufB[hp*2+1][k4*4], wv);
            }
            bufX[hp*2  ][d] = a0;
            bufX[hp*2+1][d] = a1;
            xg[(size_t)(r0 + hp*2    )*256 + d] = a0;   // halo for wg rb+1
            xg[(size_t)(r0 + hp*2 + 1)*256 + d] = a1;
        }
        // ---- S1: neighbor handshake (conv needs wg rb-1's last 3 rows) ----
        __syncthreads();
        if (t == 0) {
            __hip_atomic_fetch_add(s1slot + rb, 1u, __ATOMIC_RELEASE, __HIP_MEMORY_SCOPE_AGENT);
            if (rb > 0) {
                while (__hip_atomic_load(s1slot + rb - 1, __ATOMIC_RELAXED, __HIP_MEMORY_SCOPE_AGENT) == 0u)
                    __builtin_amdgcn_s_sleep(1);
            }
        }
        __syncthreads();

        // ---- conv + silu -> u in bufA (own rows from LDS, halo via aload) --
        {
            int d = t & 255, half = t >> 8;           // 2 rows per thread
            int rbase = s*64;
            float4 cw = *(const float4*)&conv_w[((size_t)layer*256 + d)*4];
            float cb = conv_b[layer*256 + d];
            if (half == 0) {
                float x0 = (l0-3 >= 0) ? aload(&xg[(size_t)(rbase+l0-3)*256 + d]) : 0.f;
                float x1 = (l0-2 >= 0) ? aload(&xg[(size_t)(rbase+l0-2)*256 + d]) : 0.f;
                float x2 = (l0-1 >= 0) ? aload(&xg[(size_t)(rbase+l0-1)*256 + d]) : 0.f;
                float x3 = bufX[0][d];
                float x4 = bufX[1][d];
                bufA[0][d] = silu_f(cb + cw.x*x0 + cw.y*x1 + cw.z*x2 + cw.w*x3);
                bufA[1][d] = silu_f(cb + cw.x*x1 + cw.y*x2 + cw.z*x3 + cw.w*x4);
            } else {
                float x0 = (l0-1 >= 0) ? aload(&xg[(size_t)(rbase+l0-1)*256 + d]) : 0.f;
                float x1 = bufX[0][d];
                float x2 = bufX[1][d];
                float x3 = bufX[2][d];
                float x4 = bufX[3][d];
                bufA[2][d] = silu_f(cb + cw.x*x0 + cw.y*x1 + cw.z*x2 + cw.w*x3);
                bufA[3][d] = silu_f(cb + cw.x*x1 + cw.y*x2 + cw.z*x3 + cw.w*x4);
            }
        }
        __syncthreads();

        // ---- xproj: xdbl[4][40], K=256 from LDS ----
        if (t < 160) {
            int rq = t & 3, jx = t >> 2;
            const float* xw = x_proj_w + ((size_t)layer*40 + jx)*256;
            float acc = 0.f;
            #pragma unroll 16
            for (int k4 = 0; k4 < 64; ++k4)
                acc += dot4(*(const float4*)&bufA[rq][k4*4], *(const float4*)&xw[k4*4]);
            xdS[rq][jx] = acc;
        }
        __syncthreads();

        // ---- dt = softplus(...) ; write dt and du = dt*u ----
        {
            int d = t & 255, half = t >> 8;
            const float* dw = dt_proj_w + ((size_t)layer*256 + d)*8;
            float4 wa = *(const float4*)&dw[0];
            float4 wb = *(const float4*)&dw[4];
            float b = dt_proj_b[layer*256 + d];
            #pragma unroll
            for (int q = 0; q < 2; ++q) {
                int rloc = half*2 + q;
                float4 xa = *(const float4*)&xdS[rloc][0];
                float4 xb = *(const float4*)&xdS[rloc][4];
                float pre = b + dot4(xa, wa) + dot4(xb, wb);
                float sp = (pre > 20.f) ? pre : log1pf(__expf(pre));
                dtg[(size_t)(r0+rloc)*256 + d] = sp;
                dug[(size_t)(r0+rloc)*256 + d] = sp * bufA[rloc][d];
            }
        }
        // ---- pack B,C ----
        if (t < 128) {
            int r = t >> 5, j = t & 31;
            bcg[(size_t)(r0+r)*32 + j] = xdS[r][8 + j];
        }
        seq_barrier(s2slot);   // S2: dt, du, B, C visible within seq

        // ---- stage scan inputs (parallel, all 512 threads, 4 dwords each) --
        if (t < 256) {
            int l = t >> 2, q = t & 3;
            const float* p = &dtg[(size_t)(s*64+l)*256 + d0 + q*4];
            sdt[l][q*4]   = aload(p);     sdt[l][q*4+1] = aload(p+1);
            sdt[l][q*4+2] = aload(p+2);   sdt[l][q*4+3] = aload(p+3);
        } else {
            int tt = t - 256; int l = tt >> 2, q = tt & 3;
            const float* p = &dug[(size_t)(s*64+l)*256 + d0 + q*4];
            sdu[l][q*4]   = aload(p);     sdu[l][q*4+1] = aload(p+1);
            sdu[l][q*4+2] = aload(p+2);   sdu[l][q*4+3] = aload(p+3);
        }
        {
            int l = t >> 3, q = t & 7;
            const float* p = &bcg[(size_t)(s*64+l)*32 + q*4];
            sbc[l][q*4]   = aload(p);     sbc[l][q*4+1] = aload(p+1);
            sbc[l][q*4+2] = aload(p+2);   sbc[l][q*4+3] = aload(p+3);
        }
        __syncthreads();

        // ---- scan window: wave0 scans ; waves 4-7 z-GEMM ----
        if (t < 64) {
            const int dloc = t >> 2, sub = t & 3, d = d0 + dloc;
            const float* Ab = A_log + ((size_t)layer*256 + d)*16 + sub*4;
            float A0 = -__expf(Ab[0]), A1 = -__expf(Ab[1]);
            float A2 = -__expf(Ab[2]), A3 = -__expf(Ab[3]);
            float h0 = 0.f, h1v = 0.f, h2v = 0.f, h3v = 0.f;
            #pragma unroll 4
            for (int l = 0; l < 64; ++l) {
                float dtv = sdt[l][dloc];
                float duv = sdu[l][dloc];
                float4 B4, C4;
                B4.x = sbc[l][sub*4];      B4.y = sbc[l][sub*4+1];
                B4.z = sbc[l][sub*4+2];    B4.w = sbc[l][sub*4+3];
                C4.x = sbc[l][16+sub*4];   C4.y = sbc[l][16+sub*4+1];
                C4.z = sbc[l][16+sub*4+2]; C4.w = sbc[l][16+sub*4+3];
                float dA, yp;
                dA = __expf(dtv*A0); h0  = dA*h0  + duv*B4.x; yp  = h0 *C4.x;
                dA = __expf(dtv*A1); h1v = dA*h1v + duv*B4.y; yp += h1v*C4.y;
                dA = __expf(dtv*A2); h2v = dA*h2v + duv*B4.z; yp += h2v*C4.z;
                dA = __expf(dtv*A3); h3v = dA*h3v + duv*B4.w; yp += h3v*C4.w;
                yp += __shfl_xor(yp, 1);
                yp += __shfl_xor(yp, 2);
                if (sub == 0) yg[(size_t)(s*64+l)*256 + d] = yp;
            }
        } else if (t >= 256) {
            // in-GEMM z-half: col dz, 4 rows, hn still in bufB
            const int dz = t - 256;
            const float* w = in_proj_w + ((size_t)layer*512 + 256 + dz)*128;
            float a0=0.f, a1=0.f, a2=0.f, a3=0.f;
            #pragma unroll 16
            for (int k4 = 0; k4 < 32; ++k4) {
                float4 wv = *(const float4*)&w[k4*4];
                a0 += dot4(*(const float4*)&bufB[0][k4*4], wv);
                a1 += dot4(*(const float4*)&bufB[1][k4*4], wv);
                a2 += dot4(*(const float4*)&bufB[2][k4*4], wv);
                a3 += dot4(*(const float4*)&bufB[3][k4*4], wv);
            }
            bufZ[0][dz] = a0;  bufZ[1][dz] = a1;
            bufZ[2][dz] = a2;  bufZ[3][dz] = a3;
        }
        seq_barrier(s3slot);   // S3: y visible within seq (+ bufZ via barrier)

        // ---- gate: g = (y + u*Dsk) * silu(z)  (u in bufA, z in bufZ) ----
        {
            int d = t & 255, half = t >> 8;
            float Dsk = D_skip[layer*256 + d];
            #pragma unroll
            for (int q = 0; q < 2; ++q) {
                int rloc = half*2 + q; int r = r0 + rloc;
                float z = bufZ[rloc][d];
                float yv = aload(&yg[(size_t)r*256 + d]) + bufA[rloc][d]*Dsk;
                bufG[rloc][d] = yv * silu_f(z);
            }
        }
        __syncthreads();

        // ---- out-GEMM, K split 4 ways, LDS reduce ----
        {
            const int cc = t & 127, kc = t >> 7;
            const float* w = out_proj_w + ((size_t)layer*128 + cc)*256 + kc*64;
            float p0=0.f, p1=0.f, p2=0.f, p3=0.f;
            #pragma unroll
            for (int k4 = 0; k4 < 16; ++k4) {
                float4 wv = *(const float4*)&w[k4*4];
                p0 += dot4(*(const float4*)&bufG[0][kc*64 + k4*4], wv);
                p1 += dot4(*(const float4*)&bufG[1][kc*64 + k4*4], wv);
                p2 += dot4(*(const float4*)&bufG[2][kc*64 + k4*4], wv);
                p3 += dot4(*(const float4*)&bufG[3][kc*64 + k4*4], wv);
            }
            pOut[kc][0][cc] = p0;  pOut[kc][1][cc] = p1;
            pOut[kc][2][cc] = p2;  pOut[kc][3][cc] = p3;
        }
        __syncthreads();
        resid += pOut[0][h][c] + pOut[1][h][c] + pOut[2][h][c] + pOut[3][h][c];
        __syncthreads();
    }

    // ===================== final: row 63 of each seq =====================
    if (t == 0) anyv = 0;
    __syncthreads();
    if (rb == 15) {
        if (t < 64 && mask[s*4096 + t] != 0) anyv = 1;   // benign race
        float sq = wave_red_sum(resid*resid);
        if ((t & 63) == 0) part[wave] = sq;
    }
    __syncthreads();
    if (rb == 15 && h == 3) {
        float sr = part[6] + part[7];
        float sc = rsqrtf(sr*(1.0f/128.0f) + 1e-5f);
        float o  = resid * sc * norm_f_w[c];
        out[s*128 + c] = anyv ? o : 0.f;
    }
}

// ---------------------------------------------------------------------------
extern "C" void kernel_launch(void* const* d_in, const int* in_sizes, int n_in,
                              void* d_out, int out_size, void* d_ws, size_t ws_size,
                              hipStream_t stream) {
    (void)in_sizes; (void)n_in; (void)out_size; (void)ws_size;
    const float* mha_in     = (const float*)d_in[0];
    const int*   mask       = (const int*)  d_in[1];
    const float* mlp_w1     = (const float*)d_in[2];
    const float* mlp_b1     = (const float*)d_in[3];
    const float* mlp_w2     = (const float*)d_in[4];
    const float* mlp_b2     = (const float*)d_in[5];
    const float* in_proj_w  = (const float*)d_in[6];
    const float* conv_w     = (const float*)d_in[7];
    const float* conv_b     = (const float*)d_in[8];
    const float* x_proj_w   = (const float*)d_in[9];
    const float* dt_proj_w  = (const float*)d_in[10];
    const float* dt_proj_b  = (const float*)d_in[11];
    const float* A_log      = (const float*)d_in[12];
    const float* D_skip     = (const float*)d_in[13];
    const float* out_proj_w = (const float*)d_in[14];
    const float* blk_norm_w = (const float*)d_in[15];
    const float* norm_f_w   = (const float*)d_in[16];
    float* ws  = (float*)d_ws;
    float* out = (float*)d_out;

    // zero the barrier flag slots (graph-capture-safe)
    hipMemsetAsync(d_ws, 0, 2048, stream);

    // Regular launch: 64 wgs <= 256 CUs with 1-wg/CU resources => all
    // co-resident; spin barriers are deadlock-free.
    fused_kernel<<<NWG, NTHR, 0, stream>>>(
        mha_in, mask, mlp_w1, mlp_b1, mlp_w2, mlp_b2,
        in_proj_w, conv_w, conv_b, x_proj_w, dt_proj_w, dt_proj_b,
        A_log, D_skip, out_proj_w, blk_norm_w, norm_f_w, ws, out);
}

// Round 8
// 250.346 us; speedup vs baseline: 6.0957x; 1.0143x over previous
//
#include <hip/hip_runtime.h>
#include <math.h>

#define NWG  64
#define NTHR 512

// ws layout (floats). First 512 floats = barrier flag slots (uint), zeroed by
// the hipMemsetAsync below:
//   S1 (per-wg xg handshake): slot (layer*4+s)*16 + rb          -> 0..255
//   S2 (per-seq full):        slot 256 + layer*4 + s            -> 256..271
//   S3 (per-seq full):        slot 272 + layer*4 + s            -> 272..287
#define WS_XG 512                   // 256 rows x 256 (x-half of in_proj output)
#define WS_DT (WS_XG + 65536)       // 256 x 256
#define WS_DU (WS_DT + 65536)       // 256 x 256  (du = dt*u)
#define WS_BC (WS_DU + 65536)       // 256 x 32
#define WS_Y  (WS_BC + 8192)        // 256 x 256

__device__ __forceinline__ float silu_f(float v) { return v / (1.0f + __expf(-v)); }
__device__ __forceinline__ float dot4(float4 a, float4 b) {
    return a.x*b.x + a.y*b.y + a.z*b.z + a.w*b.w;
}
__device__ __forceinline__ float wave_red_sum(float v) {
    v += __shfl_xor(v, 1);  v += __shfl_xor(v, 2);  v += __shfl_xor(v, 4);
    v += __shfl_xor(v, 8);  v += __shfl_xor(v, 16); v += __shfl_xor(v, 32);
    return v;
}
// Agent-coherent scalar load: reads the coherence point (MALL), bypassing
// possibly-stale local L1/L2. No cache-wide invalidate.
__device__ __forceinline__ float aload(const float* p) {
    return __hip_atomic_load(p, __ATOMIC_RELAXED, __HIP_MEMORY_SCOPE_AGENT);
}
// Agent-coherent write-through store (global_store ... sc1): lands at the
// coherence point, NO buffer_wbl2 cache walk. vmcnt tracks its completion.
__device__ __forceinline__ void astore(float* p, float v) {
    __hip_atomic_store(p, v, __ATOMIC_RELAXED, __HIP_MEMORY_SCOPE_AGENT);
}

// Full per-seq barrier (16 wgs), RELEASE-FREE protocol:
// all cross-wg data was stored write-through (astore); __syncthreads drains
// every wave's vmcnt to 0 (compiler emits s_waitcnt vmcnt(0) before
// s_barrier), so the data is AT the coherence point before the relaxed flag
// bump. Readers use aload. Zero cache-maintenance instructions.
__device__ __forceinline__ void seq_barrier(unsigned* slot) {
    __syncthreads();
    if (threadIdx.x == 0) {
        asm volatile("s_waitcnt vmcnt(0)" ::: "memory");
        __hip_atomic_fetch_add(slot, 1u, __ATOMIC_RELAXED, __HIP_MEMORY_SCOPE_AGENT);
        while (__hip_atomic_load(slot, __ATOMIC_RELAXED, __HIP_MEMORY_SCOPE_AGENT) < 16u)
            __builtin_amdgcn_s_sleep(1);
    }
    __syncthreads();
}

// 64 wgs x 512 threads, REGULAR launch. Co-residency by capacity: grid 64 <=
// 256 CUs, 1 wg/CU worth of resources, so all wgs are resident immediately
// and the spin barriers cannot deadlock.
// seq = wg & 3, row-block rb = wg >> 2 : owns rows l0..l0+3 (l0 = rb*4).
// Register residual: thread t owns (row h = t>>7, col c = t&127).
__global__ __launch_bounds__(NTHR, 1) void fused_kernel(
    const float* __restrict__ mha_in, const int* __restrict__ mask,
    const float* __restrict__ mlp_w1, const float* __restrict__ mlp_b1,
    const float* __restrict__ mlp_w2, const float* __restrict__ mlp_b2,
    const float* __restrict__ in_proj_w, const float* __restrict__ conv_w,
    const float* __restrict__ conv_b, const float* __restrict__ x_proj_w,
    const float* __restrict__ dt_proj_w, const float* __restrict__ dt_proj_b,
    const float* __restrict__ A_log, const float* __restrict__ D_skip,
    const float* __restrict__ out_proj_w, const float* __restrict__ blk_norm_w,
    const float* __restrict__ norm_f_w,
    float* __restrict__ ws, float* __restrict__ out)
{
    const int wg = blockIdx.x;
    const int t  = threadIdx.x;
    const int s  = wg & 3;           // sequence
    const int rb = wg >> 2;          // row-block within seq (0..15)
    const int l0 = rb * 4;           // first owned local row
    const int r0 = s*64 + l0;        // first owned global row
    const int d0 = rb * 16;          // scan channel base
    const int h  = t >> 7;           // owned row 0..3
    const int c  = t & 127;          // owned col
    const int wave = t >> 6;

    unsigned* bar = (unsigned*)ws;
    float* xg  = ws + WS_XG;
    float* dtg = ws + WS_DT;
    float* dug = ws + WS_DU;
    float* bcg = ws + WS_BC;
    float* yg  = ws + WS_Y;

    __shared__ float bufX[4][256];   // x (conv input, own rows)
    __shared__ float bufZ[4][256];   // z (computed during scan window)
    __shared__ float bufA[4][256];   // h1 / u (kept live through gate)
    __shared__ float bufG[4][256];   // g = (y + u*Dsk)*silu(z)
    __shared__ float bufB[4][128];   // x_in / hn
    __shared__ float xdS[4][40];
    __shared__ float sdt[64][17];    // staged dt   [l][ch]  (+1 pad: banks)
    __shared__ float sdu[64][17];    // staged dt*u [l][ch]
    __shared__ float sbc[64][33];    // staged B,C  [l][0..15=B,16..31=C]
    __shared__ float pOut[4][4][128];
    __shared__ float part[8];
    __shared__ int   anyv;

    float resid;

    // ===================== MLP preamble (row-local) =====================
    bufB[h][c] = mha_in[(size_t)s*524288 + (size_t)(l0 + h)*128 + c];
    __syncthreads();
    {
        const float* w = mlp_w1 + (size_t)c * 128;
        float acc = 0.f;
        #pragma unroll 16
        for (int k4 = 0; k4 < 32; ++k4)
            acc += dot4(*(const float4*)&bufB[h][k4*4], *(const float4*)&w[k4*4]);
        float v = acc + mlp_b1[c];
        v = 0.5f*v*(1.0f + erff(v*0.70710678118f));
        bufA[h][c] = v;
    }
    __syncthreads();
    {
        const float* w = mlp_w2 + (size_t)c * 128;
        float acc = 0.f;
        #pragma unroll 16
        for (int k4 = 0; k4 < 32; ++k4)
            acc += dot4(*(const float4*)&bufA[h][k4*4], *(const float4*)&w[k4*4]);
        resid = acc + mlp_b2[c];
    }
    __syncthreads();

    // ===================== layer loop =====================
    for (int layer = 0; layer < 4; ++layer) {
        unsigned* s1slot = bar + (layer*4 + s)*16;
        unsigned* s2slot = bar + 256 + layer*4 + s;
        unsigned* s3slot = bar + 272 + layer*4 + s;

        // ---- rmsnorm(resid) -> bufB (hn) ----
        {
            float sq = wave_red_sum(resid*resid);
            if ((t & 63) == 0) part[wave] = sq;
        }
        __syncthreads();
        {
            float sr = part[h*2] + part[h*2 + 1];
            float sc = rsqrtf(sr*(1.0f/128.0f) + 1e-5f);
            bufB[h][c] = resid * sc * blk_norm_w[layer*128 + c];
        }
        __syncthreads();

        // ---- in-GEMM x-half: cols 0..255, 2 rows/thread -> bufX + xg ----
        {
            const int d = t & 255, hp = t >> 8;      // rows hp*2, hp*2+1
            const float* w = in_proj_w + ((size_t)layer*512 + d)*128;
            float a0 = 0.f, a1 = 0.f;
            #pragma unroll 16
            for (int k4 = 0; k4 < 32; ++k4) {
                float4 wv = *(const float4*)&w[k4*4];
                a0 += dot4(*(const float4*)&bufB[hp*2  ][k4*4], wv);
                a1 += dot4(*(const float4*)&bufB[hp*2+1][k4*4], wv);
            }
            bufX[hp*2  ][d] = a0;
            bufX[hp*2+1][d] = a1;
            astore(&xg[(size_t)(r0 + hp*2    )*256 + d], a0);  // halo for rb+1
            astore(&xg[(size_t)(r0 + hp*2 + 1)*256 + d], a1);
        }
        // ---- S1: neighbor handshake (conv needs wg rb-1's last 3 rows) ----
        __syncthreads();   // drains all waves' vmcnt -> xg stores at MALL
        if (t == 0) {
            asm volatile("s_waitcnt vmcnt(0)" ::: "memory");
            __hip_atomic_fetch_add(s1slot + rb, 1u, __ATOMIC_RELAXED, __HIP_MEMORY_SCOPE_AGENT);
            if (rb > 0) {
                while (__hip_atomic_load(s1slot + rb - 1, __ATOMIC_RELAXED, __HIP_MEMORY_SCOPE_AGENT) == 0u)
                    __builtin_amdgcn_s_sleep(1);
            }
        }
        __syncthreads();

        // ---- conv + silu -> u in bufA (own rows from LDS, halo via aload) --
        {
            int d = t & 255, half = t >> 8;           // 2 rows per thread
            int rbase = s*64;
            float4 cw = *(const float4*)&conv_w[((size_t)layer*256 + d)*4];
            float cb = conv_b[layer*256 + d];
            if (half == 0) {
                float x0 = (l0-3 >= 0) ? aload(&xg[(size_t)(rbase+l0-3)*256 + d]) : 0.f;
                float x1 = (l0-2 >= 0) ? aload(&xg[(size_t)(rbase+l0-2)*256 + d]) : 0.f;
                float x2 = (l0-1 >= 0) ? aload(&xg[(size_t)(rbase+l0-1)*256 + d]) : 0.f;
                float x3 = bufX[0][d];
                float x4 = bufX[1][d];
                bufA[0][d] = silu_f(cb + cw.x*x0 + cw.y*x1 + cw.z*x2 + cw.w*x3);
                bufA[1][d] = silu_f(cb + cw.x*x1 + cw.y*x2 + cw.z*x3 + cw.w*x4);
            } else {
                float x0 = (l0-1 >= 0) ? aload(&xg[(size_t)(rbase+l0-1)*256 + d]) : 0.f;
                float x1 = bufX[0][d];
                float x2 = bufX[1][d];
                float x3 = bufX[2][d];
                float x4 = bufX[3][d];
                bufA[2][d] = silu_f(cb + cw.x*x0 + cw.y*x1 + cw.z*x2 + cw.w*x3);
                bufA[3][d] = silu_f(cb + cw.x*x1 + cw.y*x2 + cw.z*x3 + cw.w*x4);
            }
        }
        __syncthreads();

        // ---- xproj: xdbl[4][40], K=256 from LDS ; B,C -> bcg inline ----
        if (t < 160) {
            int rq = t & 3, jx = t >> 2;
            const float* xw = x_proj_w + ((size_t)layer*40 + jx)*256;
            float acc = 0.f;
            #pragma unroll 16
            for (int k4 = 0; k4 < 64; ++k4)
                acc += dot4(*(const float4*)&bufA[rq][k4*4], *(const float4*)&xw[k4*4]);
            xdS[rq][jx] = acc;
            if (jx >= 8)
                astore(&bcg[(size_t)(r0+rq)*32 + (jx-8)], acc);
        }
        __syncthreads();

        // ---- dt = softplus(...) ; write dt and du = dt*u (write-through) --
        {
            int d = t & 255, half = t >> 8;
            const float* dw = dt_proj_w + ((size_t)layer*256 + d)*8;
            float4 wa = *(const float4*)&dw[0];
            float4 wb = *(const float4*)&dw[4];
            float b = dt_proj_b[layer*256 + d];
            #pragma unroll
            for (int q = 0; q < 2; ++q) {
                int rloc = half*2 + q;
                float4 xa = *(const float4*)&xdS[rloc][0];
                float4 xb = *(const float4*)&xdS[rloc][4];
                float pre = b + dot4(xa, wa) + dot4(xb, wb);
                float sp = (pre > 20.f) ? pre : log1pf(__expf(pre));
                astore(&dtg[(size_t)(r0+rloc)*256 + d], sp);
                astore(&dug[(size_t)(r0+rloc)*256 + d], sp * bufA[rloc][d]);
            }
        }
        seq_barrier(s2slot);   // S2: dt, du, B, C at coherence point

        // ---- stage scan inputs (parallel, all 512 threads, 4 dwords each) --
        if (t < 256) {
            int l = t >> 2, q = t & 3;
            const float* p = &dtg[(size_t)(s*64+l)*256 + d0 + q*4];
            sdt[l][q*4]   = aload(p);     sdt[l][q*4+1] = aload(p+1);
            sdt[l][q*4+2] = aload(p+2);   sdt[l][q*4+3] = aload(p+3);
        } else {
            int tt = t - 256; int l = tt >> 2, q = tt & 3;
            const float* p = &dug[(size_t)(s*64+l)*256 + d0 + q*4];
            sdu[l][q*4]   = aload(p);     sdu[l][q*4+1] = aload(p+1);
            sdu[l][q*4+2] = aload(p+2);   sdu[l][q*4+3] = aload(p+3);
        }
        {
            int l = t >> 3, q = t & 7;
            const float* p = &bcg[(size_t)(s*64+l)*32 + q*4];
            sbc[l][q*4]   = aload(p);     sbc[l][q*4+1] = aload(p+1);
            sbc[l][q*4+2] = aload(p+2);   sbc[l][q*4+3] = aload(p+3);
        }
        __syncthreads();

        // ---- scan window: wave0 scans ; waves 4-7 z-GEMM ----
        if (t < 64) {
            const int dloc = t >> 2, sub = t & 3, d = d0 + dloc;
            const float* Ab = A_log + ((size_t)layer*256 + d)*16 + sub*4;
            float A0 = -__expf(Ab[0]), A1 = -__expf(Ab[1]);
            float A2 = -__expf(Ab[2]), A3 = -__expf(Ab[3]);
            float h0 = 0.f, h1v = 0.f, h2v = 0.f, h3v = 0.f;
            #pragma unroll 4
            for (int l = 0; l < 64; ++l) {
                float dtv = sdt[l][dloc];
                float duv = sdu[l][dloc];
                float4 B4, C4;
                B4.x = sbc[l][sub*4];      B4.y = sbc[l][sub*4+1];
                B4.z = sbc[l][sub*4+2];    B4.w = sbc[l][sub*4+3];
                C4.x = sbc[l][16+sub*4];   C4.y = sbc[l][16+sub*4+1];
                C4.z = sbc[l][16+sub*4+2]; C4.w = sbc[l][16+sub*4+3];
                float dA, yp;
                dA = __expf(dtv*A0); h0  = dA*h0  + duv*B4.x; yp  = h0 *C4.x;
                dA = __expf(dtv*A1); h1v = dA*h1v + duv*B4.y; yp += h1v*C4.y;
                dA = __expf(dtv*A2); h2v = dA*h2v + duv*B4.z; yp += h2v*C4.z;
                dA = __expf(dtv*A3); h3v = dA*h3v + duv*B4.w; yp += h3v*C4.w;
                yp += __shfl_xor(yp, 1);
                yp += __shfl_xor(yp, 2);
                if (sub == 0) astore(&yg[(size_t)(s*64+l)*256 + d], yp);
            }
        } else if (t >= 256) {
            // in-GEMM z-half: col dz, 4 rows, hn still in bufB
            const int dz = t - 256;
            const float* w = in_proj_w + ((size_t)layer*512 + 256 + dz)*128;
            float a0=0.f, a1=0.f, a2=0.f, a3=0.f;
            #pragma unroll 16
            for (int k4 = 0; k4 < 32; ++k4) {
                float4 wv = *(const float4*)&w[k4*4];
                a0 += dot4(*(const float4*)&bufB[0][k4*4], wv);
                a1 += dot4(*(const float4*)&bufB[1][k4*4], wv);
                a2 += dot4(*(const float4*)&bufB[2][k4*4], wv);
                a3 += dot4(*(const float4*)&bufB[3][k4*4], wv);
            }
            bufZ[0][dz] = a0;  bufZ[1][dz] = a1;
            bufZ[2][dz] = a2;  bufZ[3][dz] = a3;
        }
        seq_barrier(s3slot);   // S3: y at coherence point (+ bufZ via barrier)

        // ---- gate: g = (y + u*Dsk) * silu(z)  (u in bufA, z in bufZ) ----
        {
            int d = t & 255, half = t >> 8;
            float Dsk = D_skip[layer*256 + d];
            #pragma unroll
            for (int q = 0; q < 2; ++q) {
                int rloc = half*2 + q; int r = r0 + rloc;
                float z = bufZ[rloc][d];
                float yv = aload(&yg[(size_t)r*256 + d]) + bufA[rloc][d]*Dsk;
                bufG[rloc][d] = yv * silu_f(z);
            }
        }
        __syncthreads();

        // ---- out-GEMM, K split 4 ways, LDS reduce ----
        {
            const int cc = t & 127, kc = t >> 7;
            const float* w = out_proj_w + ((size_t)layer*128 + cc)*256 + kc*64;
            float p0=0.f, p1=0.f, p2=0.f, p3=0.f;
            #pragma unroll
            for (int k4 = 0; k4 < 16; ++k4) {
                float4 wv = *(const float4*)&w[k4*4];
                p0 += dot4(*(const float4*)&bufG[0][kc*64 + k4*4], wv);
                p1 += dot4(*(const float4*)&bufG[1][kc*64 + k4*4], wv);
                p2 += dot4(*(const float4*)&bufG[2][kc*64 + k4*4], wv);
                p3 += dot4(*(const float4*)&bufG[3][kc*64 + k4*4], wv);
            }
            pOut[kc][0][cc] = p0;  pOut[kc][1][cc] = p1;
            pOut[kc][2][cc] = p2;  pOut[kc][3][cc] = p3;
        }
        __syncthreads();
        resid += pOut[0][h][c] + pOut[1][h][c] + pOut[2][h][c] + pOut[3][h][c];
        __syncthreads();
    }

    // ===================== final: row 63 of each seq =====================
    if (t == 0) anyv = 0;
    __syncthreads();
    if (rb == 15) {
        if (t < 64 && mask[s*4096 + t] != 0) anyv = 1;   // benign race
        float sq = wave_red_sum(resid*resid);
        if ((t & 63) == 0) part[wave] = sq;
    }
    __syncthreads();
    if (rb == 15 && h == 3) {
        float sr = part[6] + part[7];
        float sc = rsqrtf(sr*(1.0f/128.0f) + 1e-5f);
        float o  = resid * sc * norm_f_w[c];
        out[s*128 + c] = anyv ? o : 0.f;
    }
}

// ---------------------------------------------------------------------------
extern "C" void kernel_launch(void* const* d_in, const int* in_sizes, int n_in,
                              void* d_out, int out_size, void* d_ws, size_t ws_size,
                              hipStream_t stream) {
    (void)in_sizes; (void)n_in; (void)out_size; (void)ws_size;
    const float* mha_in     = (const float*)d_in[0];
    const int*   mask       = (const int*)  d_in[1];
    const float* mlp_w1     = (const float*)d_in[2];
    const float* mlp_b1     = (const float*)d_in[3];
    const float* mlp_w2     = (const float*)d_in[4];
    const float* mlp_b2     = (const float*)d_in[5];
    const float* in_proj_w  = (const float*)d_in[6];
    const float* conv_w     = (const float*)d_in[7];
    const float* conv_b     = (const float*)d_in[8];
    const float* x_proj_w   = (const float*)d_in[9];
    const float* dt_proj_w  = (const float*)d_in[10];
    const float* dt_proj_b  = (const float*)d_in[11];
    const float* A_log      = (const float*)d_in[12];
    const float* D_skip     = (const float*)d_in[13];
    const float* out_proj_w = (const float*)d_in[14];
    const float* blk_norm_w = (const float*)d_in[15];
    const float* norm_f_w   = (const float*)d_in[16];
    float* ws  = (float*)d_ws;
    float* out = (float*)d_out;

    // zero the barrier flag slots (graph-capture-safe)
    hipMemsetAsync(d_ws, 0, 2048, stream);

    // Regular launch: 64 wgs <= 256 CUs with 1-wg/CU resources => all
    // co-resident; spin barriers are deadlock-free.
    fused_kernel<<<NWG, NTHR, 0, stream>>>(
        mha_in, mask, mlp_w1, mlp_b1, mlp_w2, mlp_b2,
        in_proj_w, conv_w, conv_b, x_proj_w, dt_proj_w, dt_proj_b,
        A_log, D_skip, out_proj_w, blk_norm_w, norm_f_w, ws, out);
}